// Round 9
// baseline (3827.160 us; speedup 1.0000x reference)
//
#include <hip/hip_runtime.h>
#include <hip/hip_bf16.h>
#include <cstdint>

#define CB 16
#define CK 64
#define CW 2048
#define CL 2112
#define CD 512
#define CDH 256
#define CDFF 2048
#define CNL 4
#define CROWS (CB*CL)
#define NCH 2                // FFN row chunks
#define RCH2 (CROWS/NCH)     // 16896 = 132*128

typedef __attribute__((ext_vector_type(8))) short bf16x8;
typedef __attribute__((ext_vector_type(4))) float f32x4;

__device__ __forceinline__ float bf2f(unsigned short u) {
    union { unsigned int i; float f; } x; x.i = ((unsigned int)u) << 16; return x.f;
}

__device__ __forceinline__ void load_lds16(const void* g, void* l) {
    __builtin_amdgcn_global_load_lds(
        (const __attribute__((address_space(1))) void*)g,
        (__attribute__((address_space(3))) void*)l, 16, 0, 0);
}

// XCD-aware bijective block swizzle (m204): only applied when nwg%8==0.
__device__ __forceinline__ void xcd_swizzle(int& bx, int& by) {
    const int gx = gridDim.x, nwg = gx * gridDim.y;
    if ((nwg & 7) == 0) {
        const int flat = by * gx + bx;
        const int cpx = nwg >> 3;
        const int swz = (flat & 7) * cpx + (flat >> 3);
        bx = swz % gx; by = swz / gx;
    }
}

// ---------------- GEMM 128x128: C[MxN] = A[MxK] @ Bt[NxK]^T, bf16 in, fp32 acc ----------------
// epi 0: C bf16 = acc ; epi 1: bf16 relu(acc+bias) ; epi 2: bf16 acc*scale ; epi 3: fp32 C += acc+bias
// LDS XOR-swizzled; double-buffered, counted vmcnt (proven rounds 1/3/5/6/8).
#define BM 128
#define BN 128
#define BKG 64

__global__ __launch_bounds__(256) void gemm_bt(
    const short* __restrict__ A, const short* __restrict__ Bt, void* __restrict__ C,
    const float* __restrict__ bias, int M, int N, int Kd,
    int lda, int ldb, int ldc, long sA, long sB, long sC, float scale, int epi,
    int ksplit)
{
    __shared__ short lA[2][BM * BKG];
    __shared__ short lB[2][BN * BKG];
    const int tid = threadIdx.x;
    const int wave = tid >> 6, lane = tid & 63;
    const int wy = wave >> 1, wx = wave & 1;
    const int lr = lane & 15, quad = lane >> 4;
    int bx = blockIdx.x, by = blockIdx.y;
    xcd_swizzle(bx, by);
    const int m0 = by * BM, n0 = bx * BN;
    const int z = blockIdx.z;
    const short* Ab = A + (size_t)z * sA;
    const short* Bb = Bt + (size_t)z * sB;

    f32x4 acc[4][4];
#pragma unroll
    for (int i = 0; i < 4; i++)
#pragma unroll
        for (int j = 0; j < 4; j++) acc[i][j] = (f32x4){0.f, 0.f, 0.f, 0.f};

    const int sRow = lane >> 3;                       // 0..7
    const int sCol = (((lane & 7) ^ sRow) << 3);      // swizzled chunk * 8 shorts

    int kbeg = 0, kend = Kd;
    if (ksplit > 1) { const int kc = Kd / ksplit; kbeg = z * kc; kend = kbeg + kc; }
    const int nsteps = (kend - kbeg) / BKG;

    auto stage = [&](int buf, int k0) {
#pragma unroll
        for (int n = 0; n < 4; ++n) {
            const int c = wave * 4 + n;
            int ar = m0 + c * 8 + sRow; if (ar > M - 1) ar = M - 1;
            load_lds16(Ab + (size_t)ar * lda + k0 + sCol, &lA[buf][c * 512]);
            int br = n0 + c * 8 + sRow; if (br > N - 1) br = N - 1;
            load_lds16(Bb + (size_t)br * ldb + k0 + sCol, &lB[buf][c * 512]);
        }
    };

    stage(0, kbeg);
    for (int t = 0; t < nsteps; ++t) {
        const int cur = t & 1;
        if (t + 1 < nsteps) {
            stage(cur ^ 1, kbeg + (t + 1) * BKG);
            asm volatile("s_waitcnt vmcnt(8)\n\ts_barrier" ::: "memory");
        } else {
            asm volatile("s_waitcnt vmcnt(0)\n\ts_barrier" ::: "memory");
        }
#pragma unroll
        for (int kk = 0; kk < BKG; kk += 32) {
            const int k4 = kk >> 3;                   // 0 or 4
            bf16x8 av[4], bv[4];
#pragma unroll
            for (int i = 0; i < 4; i++) {
                const int ri = wy * 64 + i * 16 + lr;
                av[i] = *(const bf16x8*)&lA[cur][ri * BKG + ((((k4 + quad) ^ (ri & 7)) << 3))];
            }
#pragma unroll
            for (int j = 0; j < 4; j++) {
                const int rj = wx * 64 + j * 16 + lr;
                bv[j] = *(const bf16x8*)&lB[cur][rj * BKG + ((((k4 + quad) ^ (rj & 7)) << 3))];
            }
#pragma unroll
            for (int i = 0; i < 4; i++)
#pragma unroll
                for (int j = 0; j < 4; j++)
                    acc[i][j] = __builtin_amdgcn_mfma_f32_16x16x32_bf16(av[i], bv[j], acc[i][j], 0, 0, 0);
        }
        asm volatile("s_barrier" ::: "memory");
    }

    const int colBase = n0 + wx * 64 + lr;
    if (epi == 3) {
        float* Cp = (float*)C + (size_t)z * sC;
#pragma unroll
        for (int i = 0; i < 4; i++) {
            const int row0 = m0 + wy * 64 + i * 16 + quad * 4;
#pragma unroll
            for (int j = 0; j < 4; j++) {
                const int col = colBase + j * 16;
                if (col >= N) continue;
                const float bv_ = bias ? bias[col] : 0.f;
#pragma unroll
                for (int r = 0; r < 4; r++) {
                    const int row = row0 + r;
                    if (row < M) Cp[(size_t)row * ldc + col] += acc[i][j][r] + bv_;
                }
            }
        }
    } else {
        __hip_bfloat16* Cp = (__hip_bfloat16*)C + (size_t)z * sC;
#pragma unroll
        for (int i = 0; i < 4; i++) {
            const int row0 = m0 + wy * 64 + i * 16 + quad * 4;
#pragma unroll
            for (int j = 0; j < 4; j++) {
                const int col = colBase + j * 16;
                if (col >= N) continue;
                const float bv_ = (epi == 1) ? bias[col] : 0.f;
#pragma unroll
                for (int r = 0; r < 4; r++) {
                    const int row = row0 + r;
                    if (row < M) {
                        float v = acc[i][j][r];
                        if (epi == 1) { v += bv_; v = v > 0.f ? v : 0.f; }
                        else if (epi == 2) v *= scale;
                        Cp[(size_t)row * ldc + col] = __float2bfloat16(v);
                    }
                }
            }
        }
    }
}

// ---------------- fused flash attention, branch A v4: 32 q-rows per wave ----------------
// LDS-read-throughput was the v2 bottleneck (every wave re-read the whole K/V
// tile: 1.06 ds_read/MFMA). v4: each wave holds 2 A-fragment sets (32 q-rows,
// qf 64 VGPR + acc 128 VGPR) so each LDS B-fragment read feeds 2 MFMAs
// (0.53 reads/MFMA), and the same staged KV bytes serve 128 rows/block.
// 4 waves / 256 thr / 128 rows; KVBLK=64; LDS 80 KB; grid 272 (17 mtiles x 16 b).
// Sync: plain __syncthreads only (spill-proof; no counted vmcnt — round-4 lesson).
// pbuf rows wave-private -> no barrier between softmax and PV.
__global__ __launch_bounds__(256, 1) void flash_a(
    const short* __restrict__ q,    // [B*CL][512], q_a = cols 0..255
    const short* __restrict__ ka,   // [B][2048][256]
    const short* __restrict__ vt,   // [B][256][2048]
    short* __restrict__ out)        // hnat [B*CL][CD], writes cols 0..255
{
    __shared__ short kbuf[64 * 256];    // 32 KB, [key][dh], 32 chunks/row, phys c = logical c^(r&7)
    __shared__ short vbuf[256 * 64];    // 32 KB, [dh][key],  8 chunks/row
    __shared__ short pbuf[128 * 64];    // 16 KB, [qrow][key], wave-private rows
    const int tid = threadIdx.x, wave = tid >> 6, lane = tid & 63;
    const int lr = lane & 15, quad = lane >> 4;

    // block id -> (batch, 128-row m-tile): id&7 = XCD chunk (2 batches = 4MB L2);
    // within chunk heavy-first: mt=0 (32 tiles), mt=16 (32), 15, ..., 1.
    const int id = blockIdx.x;
    const int x = id & 7, k = id >> 3;          // k in 0..33
    const int b = 2 * x + (k >= 17);
    const int mi = (k >= 17) ? (k - 17) : k;    // 0..16
    const int mt = (mi == 0) ? 0 : (17 - mi);
    const int m0 = mt * 128;
    const short* kab = ka + (size_t)b * 2048 * 256;
    const short* vtb = vt + (size_t)b * 256 * 2048;

    // keys needed: mt=0 has cache rows (limit=CW) -> all 32 tiles;
    // else nkt = ceil((maxrow-63)/64) = maxrow>>6 with maxrow clamped to CL-1.
    const int maxr = (m0 + 127 < CL - 1) ? (m0 + 127) : (CL - 1);
    int nkt = (mt == 0) ? 32 : (maxr >> 6);
    if (nkt > 32) nkt = 32;

    // ---- Q A-fragments in registers (32 rows/wave = 2 frag sets) ----
    bf16x8 qf[2][8];
#pragma unroll
    for (int i = 0; i < 2; ++i) {
        int qr = m0 + wave * 32 + i * 16 + lr;
        if (qr > CL - 1) qr = CL - 1;
        const short* p0 = q + ((size_t)b * CL + qr) * 512;
#pragma unroll
        for (int s = 0; s < 8; ++s) qf[i][s] = *(const bf16x8*)(p0 + s * 32 + quad * 8);
    }

    // stage K tile kt: 2048 chunks of 16B, linear LDS dest, pre-swizzled global src
    auto stageK = [&](int kt) {
#pragma unroll
        for (int u = 0; u < 8; ++u) {
            const int seg = u * 4 + wave;             // 0..31
            const int idx = seg * 64 + lane;          // chunk 0..2047
            const int row = idx >> 5, cp = idx & 31;
            const int cs = cp ^ (row & 7);
            load_lds16(kab + (size_t)(kt * 64 + row) * 256 + cs * 8, kbuf + seg * 512);
        }
    };
    auto stageV = [&](int kt) {
#pragma unroll
        for (int u = 0; u < 8; ++u) {
            const int seg = u * 4 + wave;
            const int idx = seg * 64 + lane;
            const int row = idx >> 3, cp = idx & 7;   // row = dh 0..255
            const int cs = cp ^ (row & 7);
            load_lds16(vtb + (size_t)row * 2048 + kt * 64 + cs * 8, vbuf + seg * 512);
        }
    };

    f32x4 acc_o[2][16];
#pragma unroll
    for (int i = 0; i < 2; i++)
#pragma unroll
        for (int jd = 0; jd < 16; jd++) acc_o[i][jd] = (f32x4){0.f, 0.f, 0.f, 0.f};
    float m_run[2][4], l_run[2][4];
    int limit[2][4];
#pragma unroll
    for (int i = 0; i < 2; i++)
#pragma unroll
        for (int rr = 0; rr < 4; rr++) {
            m_run[i][rr] = -1e30f; l_run[i][rr] = 0.f;
            const int trow = m0 + wave * 32 + i * 16 + quad * 4 + rr;
            limit[i][rr] = (trow < CK) ? CW : (trow - (CK - 1));
        }

    for (int kt = 0; kt < nkt; ++kt) {
        stageK(kt);
        stageV(kt);
        __syncthreads();                 // staging resident (vmcnt(0)+barrier)

        // ---- QK^T: S[32 x 64] per wave; each bv feeds 2 MFMAs ----
        f32x4 s_[2][4];
#pragma unroll
        for (int i = 0; i < 2; i++)
#pragma unroll
            for (int j = 0; j < 4; j++) s_[i][j] = (f32x4){0.f, 0.f, 0.f, 0.f};
#pragma unroll
        for (int s = 0; s < 8; ++s) {
#pragma unroll
            for (int j = 0; j < 4; ++j) {
                const int rj = j * 16 + lr;
                const bf16x8 bv = *(const bf16x8*)&kbuf[rj * 256 + (((s * 4 + quad) ^ (rj & 7)) << 3)];
                s_[0][j] = __builtin_amdgcn_mfma_f32_16x16x32_bf16(qf[0][s], bv, s_[0][j], 0, 0, 0);
                s_[1][j] = __builtin_amdgcn_mfma_f32_16x16x32_bf16(qf[1][s], bv, s_[1][j], 0, 0, 0);
            }
        }

        // ---- mask + online softmax (row = wave*32 + i*16 + quad*4 + rr) ----
        const int kbase = kt * 64;
        float tmax[2][4];
#pragma unroll
        for (int i = 0; i < 2; i++)
#pragma unroll
            for (int rr = 0; rr < 4; rr++) tmax[i][rr] = -1e30f;
#pragma unroll
        for (int i = 0; i < 2; i++)
#pragma unroll
            for (int j = 0; j < 4; j++) {
                const int key = kbase + j * 16 + lr;
#pragma unroll
                for (int rr = 0; rr < 4; rr++) {
                    const float v = (key < limit[i][rr]) ? s_[i][j][rr] * 0.0625f : -1e30f;
                    s_[i][j][rr] = v;
                    tmax[i][rr] = fmaxf(tmax[i][rr], v);
                }
            }
#pragma unroll
        for (int i = 0; i < 2; i++)
#pragma unroll
            for (int rr = 0; rr < 4; rr++) {
#pragma unroll
                for (int off = 1; off < 16; off <<= 1)
                    tmax[i][rr] = fmaxf(tmax[i][rr], __shfl_xor(tmax[i][rr], off));
            }
        float scal[2][4], rowsum[2][4];
#pragma unroll
        for (int i = 0; i < 2; i++)
#pragma unroll
            for (int rr = 0; rr < 4; rr++) {
                const float mn = fmaxf(m_run[i][rr], tmax[i][rr]);
                scal[i][rr] = __expf(m_run[i][rr] - mn);
                m_run[i][rr] = mn;
                rowsum[i][rr] = 0.f;
            }
        // P = exp(S - m) -> bf16, lane-pair packed b32 writes into swizzled pbuf
#pragma unroll
        for (int i = 0; i < 2; i++)
#pragma unroll
            for (int j = 0; j < 4; j++) {
                const int cch = j * 2 + (lr >> 3);    // col chunk 0..7
#pragma unroll
                for (int rr = 0; rr < 4; rr++) {
                    const float e = __expf(s_[i][j][rr] - m_run[i][rr]);
                    rowsum[i][rr] += e;
                    const float eo = __shfl_xor(e, 1);
                    const __hip_bfloat16 b0 = __float2bfloat16(e);
                    const __hip_bfloat16 b1 = __float2bfloat16(eo);
                    const unsigned pk = ((unsigned)(*(const unsigned short*)&b1) << 16)
                                      | (unsigned)(*(const unsigned short*)&b0);
                    if (!(lane & 1)) {
                        const int prow = wave * 32 + i * 16 + quad * 4 + rr;   // local 0..127
                        *(unsigned*)&pbuf[prow * 64 + ((cch ^ (prow & 7)) << 3) + (lr & 6)] = pk;
                    }
                }
            }
#pragma unroll
        for (int i = 0; i < 2; i++)
#pragma unroll
            for (int rr = 0; rr < 4; rr++) {
#pragma unroll
                for (int off = 1; off < 16; off <<= 1)
                    rowsum[i][rr] += __shfl_xor(rowsum[i][rr], off);
                l_run[i][rr] = l_run[i][rr] * scal[i][rr] + rowsum[i][rr];
            }
#pragma unroll
        for (int i = 0; i < 2; i++)
#pragma unroll
            for (int jd = 0; jd < 16; jd++)
#pragma unroll
                for (int rr = 0; rr < 4; rr++) acc_o[i][jd][rr] *= scal[i][rr];

        // (no barrier: pbuf rows wave-private; same-wave LDS RAW compiler-ordered)

        // ---- PV: O[32 x 256] += P[32 x 64] @ V^T; each bv feeds 2 MFMAs ----
        const int pr0 = wave * 32 + lr, pr1 = pr0 + 16;
#pragma unroll
        for (int s2 = 0; s2 < 2; ++s2) {
            const bf16x8 pa0 = *(const bf16x8*)&pbuf[pr0 * 64 + (((s2 * 4 + quad) ^ (pr0 & 7)) << 3)];
            const bf16x8 pa1 = *(const bf16x8*)&pbuf[pr1 * 64 + (((s2 * 4 + quad) ^ (pr1 & 7)) << 3)];
#pragma unroll
            for (int jd = 0; jd < 16; ++jd) {
                const int rj = jd * 16 + lr;
                const bf16x8 bv = *(const bf16x8*)&vbuf[rj * 64 + (((s2 * 4 + quad) ^ (rj & 7)) << 3)];
                acc_o[0][jd] = __builtin_amdgcn_mfma_f32_16x16x32_bf16(pa0, bv, acc_o[0][jd], 0, 0, 0);
                acc_o[1][jd] = __builtin_amdgcn_mfma_f32_16x16x32_bf16(pa1, bv, acc_o[1][jd], 0, 0, 0);
            }
        }
        __syncthreads();                 // all kbuf/vbuf reads done before next staging
    }

    // ---- epilogue: O / l -> bf16, cols 0..255 of out ----
#pragma unroll
    for (int i = 0; i < 2; i++)
#pragma unroll
        for (int rr = 0; rr < 4; rr++) {
            const int trow = m0 + wave * 32 + i * 16 + quad * 4 + rr;
            if (trow >= CL) continue;
            const float rinv = 1.f / l_run[i][rr];
            __hip_bfloat16* op = (__hip_bfloat16*)out + ((size_t)b * CL + trow) * CD;
#pragma unroll
            for (int jd = 0; jd < 16; jd++)
                op[jd * 16 + lr] = __float2bfloat16(acc_o[i][jd][rr] * rinv);
        }
}

// ---------------- embedding ----------------
__global__ void embed_kernel(const int* __restrict__ cache, const int* __restrict__ seq,
                             const float* __restrict__ item, const float* __restrict__ cpos,
                             const float* __restrict__ spos, const float* __restrict__ seg,
                             float* __restrict__ h)
{
    const int row = blockIdx.x;
    const int b = row / CL, t = row - b * CL;
    const int d = threadIdx.x * 4;
    int id; const float* pos; const float* sg;
    if (t < CK) { id = cache[b * CK + t]; pos = cpos + (size_t)t * CD; sg = seg; }
    else { const int tt = t - CK; id = seq[b * CW + tt]; pos = spos + (size_t)tt * CD; sg = seg + CD; }
    const float4 ev = *(const float4*)(item + (size_t)id * CD + d);
    const float4 pv = *(const float4*)(pos + d);
    const float4 sv = *(const float4*)(sg + d);
    float4 r; r.x = ev.x + pv.x + sv.x; r.y = ev.y + pv.y + sv.y;
    r.z = ev.z + pv.z + sv.z; r.w = ev.w + pv.w + sv.w;
    *(float4*)(h + (size_t)row * CD + d) = r;
}

// ---------------- layernorm -> bf16 ----------------
__global__ __launch_bounds__(256) void ln_kernel(const float* __restrict__ h, const float* __restrict__ g,
                                                 const float* __restrict__ bb, __hip_bfloat16* __restrict__ out)
{
    const int row = blockIdx.x;
    const float* x = h + (size_t)row * CD;
    const int tid = threadIdx.x, wv = tid >> 6, lane = tid & 63;
    const float2 v = *(const float2*)(x + tid * 2);
    float s = v.x + v.y, s2 = v.x * v.x + v.y * v.y;
    __shared__ float red[8];
#pragma unroll
    for (int off = 32; off; off >>= 1) { s += __shfl_down(s, off); s2 += __shfl_down(s2, off); }
    if (lane == 0) { red[wv] = s; red[4 + wv] = s2; }
    __syncthreads();
    s = red[0] + red[1] + red[2] + red[3];
    s2 = red[4] + red[5] + red[6] + red[7];
    const float mu = s * (1.f / CD);
    const float var = s2 * (1.f / CD) - mu * mu;
    const float rs = rsqrtf(var + 1e-5f);
    const float2 gg = *(const float2*)(g + tid * 2);
    const float2 bv = *(const float2*)(bb + tid * 2);
    out[(size_t)row * CD + tid * 2 + 0] = __float2bfloat16((v.x - mu) * rs * gg.x + bv.x);
    out[(size_t)row * CD + tid * 2 + 1] = __float2bfloat16((v.y - mu) * rs * gg.y + bv.y);
}

// ---------------- softmax over 64 (branch B), wave per row ----------------
__global__ __launch_bounds__(256) void softmax_b_kernel(__hip_bfloat16* __restrict__ sb)
{
    const int row = blockIdx.x * 4 + (threadIdx.x >> 6);
    const int lane = threadIdx.x & 63;
    __hip_bfloat16* pr = sb + (size_t)row * 64;
    float x = __bfloat162float(pr[lane]);
    float m = x;
#pragma unroll
    for (int off = 32; off; off >>= 1) m = fmaxf(m, __shfl_xor(m, off));
    const float e = __expf(x - m);
    float s = e;
#pragma unroll
    for (int off = 32; off; off >>= 1) s += __shfl_xor(s, off);
    pr[lane] = __float2bfloat16(e / s);
}

// ---------------- final LN + logits ----------------
__global__ __launch_bounds__(256) void final_kernel(const float* __restrict__ h, const float* __restrict__ g,
                                                    const float* __restrict__ bb, const float* __restrict__ wev,
                                                    const float* __restrict__ bev, float* __restrict__ out)
{
    const int idx = blockIdx.x;
    const int b = idx >> 6, t = idx & 63;
    const float* x = h + ((size_t)b * CL + t) * CD;
    const int tid = threadIdx.x, wv = tid >> 6, lane = tid & 63;
    const float2 v = *(const float2*)(x + tid * 2);
    float s = v.x + v.y, s2 = v.x * v.x + v.y * v.y;
    __shared__ float red[8];
#pragma unroll
    for (int off = 32; off; off >>= 1) { s += __shfl_down(s, off); s2 += __shfl_down(s2, off); }
    if (lane == 0) { red[wv] = s; red[4 + wv] = s2; }
    __syncthreads();
    s = red[0] + red[1] + red[2] + red[3];
    s2 = red[4] + red[5] + red[6] + red[7];
    const float mu = s * (1.f / CD);
    const float var = s2 * (1.f / CD) - mu * mu;
    const float rs = rsqrtf(var + 1e-5f);
    const float2 gg = *(const float2*)(g + tid * 2);
    const float2 bv = *(const float2*)(bb + tid * 2);
    const float2 wv2 = *(const float2*)(wev + tid * 2);
    float val = ((v.x - mu) * rs * gg.x + bv.x) * wv2.x + ((v.y - mu) * rs * gg.y + bv.y) * wv2.y;
#pragma unroll
    for (int off = 32; off; off >>= 1) val += __shfl_down(val, off);
    __syncthreads();
    if (lane == 0) red[wv] = val;
    __syncthreads();
    if (tid == 0) out[idx] = red[0] + red[1] + red[2] + red[3] + bev[0];
}

// ---------------- transpose-convert: fp32 [z][R][C] -> bf16 [z][C][R] ----------------
__global__ void transpose_f32(const float* __restrict__ in, __hip_bfloat16* __restrict__ out,
                              int R, int Cc, long inzs, long outzs)
{
    __shared__ float tile[32][33];
    const size_t zi = (size_t)blockIdx.z * inzs;
    const size_t zo = (size_t)blockIdx.z * outzs;
    const int c0 = blockIdx.x * 32, r0 = blockIdx.y * 32;
    const int tx = threadIdx.x, ty = threadIdx.y;
#pragma unroll
    for (int i = ty; i < 32; i += 8)
        tile[i][tx] = in[zi + (size_t)(r0 + i) * Cc + c0 + tx];
    __syncthreads();
#pragma unroll
    for (int i = ty; i < 32; i += 8)
        out[zo + (size_t)(c0 + i) * R + r0 + tx] = __float2bfloat16(tile[tx][i]);
}

extern "C" void kernel_launch(void* const* d_in, const int* in_sizes, int n_in,
                              void* d_out, int out_size, void* d_ws, size_t ws_size,
                              hipStream_t stream)
{
    const int*   cache = (const int*)d_in[0];
    const int*   seq   = (const int*)d_in[1];
    const float* item  = (const float*)d_in[2];
    const float* cpos  = (const float*)d_in[3];
    const float* spos  = (const float*)d_in[4];
    const float* seg   = (const float*)d_in[5];
    const float* wq_s  = (const float*)d_in[6];
    const float* wk_s  = (const float*)d_in[7];
    const float* wv_s  = (const float*)d_in[8];
    const float* wq_c  = (const float*)d_in[9];
    const float* wk_c  = (const float*)d_in[10];
    const float* wv_c  = (const float*)d_in[11];
    const float* w_out = (const float*)d_in[12];
    const float* b_out = (const float*)d_in[13];
    const float* ln1_g = (const float*)d_in[14];
    const float* ln1_b = (const float*)d_in[15];
    const float* ln2_g = (const float*)d_in[16];
    const float* ln2_b = (const float*)d_in[17];
    const float* w_ff1 = (const float*)d_in[18];
    const float* b_ff1 = (const float*)d_in[19];
    const float* w_ff2 = (const float*)d_in[20];
    const float* b_ff2 = (const float*)d_in[21];
    const float* fin_g = (const float*)d_in[22];
    const float* fin_b = (const float*)d_in[23];
    const float* w_ev  = (const float*)d_in[24];
    const float* b_ev  = (const float*)d_in[25];

    // ---- workspace layout (~237 MiB) ----
    char* p = (char*)d_ws;
    auto alloc = [&](size_t bytes) { char* r = p; p += (bytes + 255) & ~(size_t)255; return (void*)r; };
    float* h    = (float*)alloc((size_t)CROWS * CD * 4);           // 69.2 MB
    short* hnat = (short*)alloc((size_t)CROWS * CD * 2);           // 34.6 MB  (hn, later attn)
    short* q    = (short*)alloc((size_t)CROWS * 512 * 2);          // 34.6 MB  (q_a | q_b)
    short* ka   = (short*)alloc((size_t)CB * CW * CDH * 2);        // 16.8 MB
    short* vt   = (short*)alloc((size_t)CB * CDH * CW * 2);        // 16.8 MB
    short* kb   = (short*)alloc((size_t)CB * 64 * CDH * 2);        // 0.5 MB
    short* vbT  = (short*)alloc((size_t)CB * CDH * 64 * 2);        // 0.5 MB
    short* sb   = (short*)alloc((size_t)CB * CL * 64 * 2);         // 4.3 MB
    short* big  = (short*)alloc((size_t)4 * CL * CW * 2);          // 34.6 MB (spare)
    short* wqT  = (short*)alloc((size_t)CNL * 512 * CD * 2);       // 2.1 MB
    short* wksT = (short*)alloc((size_t)CNL * CDH * CD * 2);
    short* wvsT = (short*)alloc((size_t)CNL * CDH * CD * 2);
    short* wkcT = (short*)alloc((size_t)CNL * CDH * CD * 2);
    short* wvcT = (short*)alloc((size_t)CNL * CDH * CD * 2);
    short* woT  = (short*)alloc((size_t)CNL * CD * CD * 2);
    short* wf1T = (short*)alloc((size_t)CNL * CDFF * CD * 2);
    short* wf2T = (short*)alloc((size_t)CNL * CD * CDFF * 2);
    // FFN intermediate (16896 x 2048 bf16 = 69.2 MB) aliases q..sb (~73.5 MB),
    // all dead during the FFN phase (recomputed every layer from hnat).
    short* ffbig = q;
    (void)big;

    const dim3 tb(32, 8);
    const long zqk = (long)CD * CDH;      // 131072
    const long zqT = (long)512 * CD;      // 262144
    transpose_f32<<<dim3(CDH/32, CD/32, CNL), tb, 0, stream>>>(wq_s, (__hip_bfloat16*)wqT, CD, CDH, zqk, zqT);
    transpose_f32<<<dim3(CDH/32, CD/32, CNL), tb, 0, stream>>>(wq_c, (__hip_bfloat16*)(wqT + (size_t)CDH * CD), CD, CDH, zqk, zqT);
    transpose_f32<<<dim3(CDH/32, CD/32, CNL), tb, 0, stream>>>(wk_s, (__hip_bfloat16*)wksT, CD, CDH, zqk, zqk);
    transpose_f32<<<dim3(CDH/32, CD/32, CNL), tb, 0, stream>>>(wv_s, (__hip_bfloat16*)wvsT, CD, CDH, zqk, zqk);
    transpose_f32<<<dim3(CDH/32, CD/32, CNL), tb, 0, stream>>>(wk_c, (__hip_bfloat16*)wkcT, CD, CDH, zqk, zqk);
    transpose_f32<<<dim3(CDH/32, CD/32, CNL), tb, 0, stream>>>(wv_c, (__hip_bfloat16*)wvcT, CD, CDH, zqk, zqk);
    transpose_f32<<<dim3(CD/32, CD/32, CNL), tb, 0, stream>>>(w_out, (__hip_bfloat16*)woT, CD, CD, (long)CD*CD, (long)CD*CD);
    transpose_f32<<<dim3(CDFF/32, CD/32, CNL), tb, 0, stream>>>(w_ff1, (__hip_bfloat16*)wf1T, CD, CDFF, (long)CD*CDFF, (long)CD*CDFF);
    transpose_f32<<<dim3(CD/32, CDFF/32, CNL), tb, 0, stream>>>(w_ff2, (__hip_bfloat16*)wf2T, CDFF, CD, (long)CD*CDFF, (long)CD*CDFF);

    embed_kernel<<<CROWS, 128, 0, stream>>>(cache, seq, item, cpos, spos, seg, h);

    const int mtilesR = CROWS / 128;          // 264
    const int mtilesL = (CL + 127) / 128;     // 17

    for (int l = 0; l < CNL; ++l) {
        const short* wqTl  = wqT  + (size_t)l * 512 * CD;
        const short* wksTl = wksT + (size_t)l * CDH * CD;
        const short* wvsTl = wvsT + (size_t)l * CDH * CD;
        const short* wkcTl = wkcT + (size_t)l * CDH * CD;
        const short* wvcTl = wvcT + (size_t)l * CDH * CD;
        const short* woTl  = woT  + (size_t)l * CD * CD;
        const short* wf1Tl = wf1T + (size_t)l * CDFF * CD;
        const short* wf2Tl = wf2T + (size_t)l * CD * CDFF;

        ln_kernel<<<CROWS, 256, 0, stream>>>(h, ln1_g + l * CD, ln1_b + l * CD, (__hip_bfloat16*)hnat);

        // q = hn @ [wq_s | wq_c]   (CROWS x 512)
        gemm_bt<<<dim3(512/128, mtilesR, 1), 256, 0, stream>>>(hnat, wqTl, q, nullptr,
            CROWS, 512, CD, CD, CD, 512, 0, 0, 0, 1.f, 0, 1);
        // k_a from hn_seq (batched over 16)
        gemm_bt<<<dim3(CDH/128, CW/128, CB), 256, 0, stream>>>(hnat + (size_t)CK * CD, wksTl, ka, nullptr,
            CW, CDH, CD, CD, CD, CDH, (long)CL * CD, 0, (long)CW * CDH, 1.f, 0, 1);
        // k_b  (M=64, N=256)
        gemm_bt<<<dim3(CDH/128, 1, CB), 256, 0, stream>>>(hnat, wkcTl, kb, nullptr,
            64, CDH, CD, CD, CD, CDH, (long)CL * CD, 0, (long)64 * CDH, 1.f, 0, 1);
        // vbT[d][key] = v_b^T  (M=256, N=64)
        gemm_bt<<<dim3(1, CDH/128, CB), 256, 0, stream>>>(wvcTl, hnat, vbT, nullptr,
            CDH, 64, CD, CD, CD, 64, 0, (long)CL * CD, (long)CDH * 64, 1.f, 0, 1);
        // vt[d][w] = v_a^T  (M=256, N=2048)
        gemm_bt<<<dim3(CW/128, CDH/128, CB), 256, 0, stream>>>(wvsTl, hnat + (size_t)CK * CD, vt, nullptr,
            CDH, CW, CD, CD, CD, CW, 0, (long)CL * CD, (long)CDH * CW, 1.f, 0, 1);

        // ---- branch B: scores_b = (q_b @ k_b^T)*scale -> softmax64 -> @ v_b ----
        gemm_bt<<<dim3(1, mtilesL, CB), 256, 0, stream>>>(q + CDH, kb, sb, nullptr,
            CL, 64, CDH, 512, CDH, 64, (long)CL * 512, (long)64 * CDH, (long)CL * 64, 0.0625f, 2, 1);
        softmax_b_kernel<<<(CB * CL) / 4, 256, 0, stream>>>((__hip_bfloat16*)sb);
        gemm_bt<<<dim3(CDH/128, mtilesL, CB), 256, 0, stream>>>(sb, vbT, hnat + CDH, nullptr,
            CL, CDH, 64, 64, 64, CD, (long)CL * 64, (long)CDH * 64, (long)CL * CD, 1.f, 0, 1);

        // ---- branch A: fused flash attention -> hnat cols [0,256) ----
        flash_a<<<dim3(272), 256, 0, stream>>>(q, ka, vt, hnat);

        // h += attn @ w_out + b_out
        gemm_bt<<<dim3(CD/128, mtilesR, 1), 256, 0, stream>>>(hnat, woTl, h, b_out + l * CD,
            CROWS, CD, CD, CD, CD, CD, 0, 0, 0, 1.f, 3, 1);

        ln_kernel<<<CROWS, 256, 0, stream>>>(h, ln2_g + l * CD, ln2_b + l * CD, (__hip_bfloat16*)hnat);

        // FFN in 2 row chunks; intermediate aliases dead q..sb region.
        for (int c = 0; c < NCH; ++c) {
            const size_t r0 = (size_t)c * RCH2;
            gemm_bt<<<dim3(CDFF/128, RCH2/128, 1), 256, 0, stream>>>(hnat + r0 * CD, wf1Tl, ffbig, b_ff1 + l * CDFF,
                RCH2, CDFF, CD, CD, CD, CDFF, 0, 0, 0, 1.f, 1, 1);
            gemm_bt<<<dim3(CD/128, RCH2/128, 1), 256, 0, stream>>>(ffbig, wf2Tl, h + r0 * CD, b_ff2 + l * CD,
                RCH2, CD, CDFF, CDFF, CDFF, CD, 0, 0, 0, 1.f, 3, 1);
        }
    }

    final_kernel<<<CB * CK, 256, 0, stream>>>(h, fin_g, fin_b, w_ev, b_ev, (float*)d_out);
}

// Round 10
// 3346.574 us; speedup vs baseline: 1.1436x; 1.1436x over previous
//
#include <hip/hip_runtime.h>
#include <hip/hip_bf16.h>
#include <cstdint>

#define CB 16
#define CK 64
#define CW 2048
#define CL 2112
#define CD 512
#define CDH 256
#define CDFF 2048
#define CNL 4
#define CROWS (CB*CL)
#define NCH 2                // FFN row chunks
#define RCH2 (CROWS/NCH)     // 16896 = 132*128

typedef __attribute__((ext_vector_type(8))) short bf16x8;
typedef __attribute__((ext_vector_type(4))) float f32x4;

__device__ __forceinline__ float bf2f(unsigned short u) {
    union { unsigned int i; float f; } x; x.i = ((unsigned int)u) << 16; return x.f;
}

__device__ __forceinline__ void load_lds16(const void* g, void* l) {
    __builtin_amdgcn_global_load_lds(
        (const __attribute__((address_space(1))) void*)g,
        (__attribute__((address_space(3))) void*)l, 16, 0, 0);
}

// XCD-aware bijective block swizzle (m204): only applied when nwg%8==0.
__device__ __forceinline__ void xcd_swizzle(int& bx, int& by) {
    const int gx = gridDim.x, nwg = gx * gridDim.y;
    if ((nwg & 7) == 0) {
        const int flat = by * gx + bx;
        const int cpx = nwg >> 3;
        const int swz = (flat & 7) * cpx + (flat >> 3);
        bx = swz % gx; by = swz / gx;
    }
}

// ---------------- GEMM 128x128: C[MxN] = A[MxK] @ Bt[NxK]^T, bf16 in, fp32 acc ----------------
// epi 0: C bf16 = acc ; epi 1: bf16 relu(acc+bias) ; epi 2: bf16 acc*scale ; epi 3: fp32 C += acc+bias
// LDS XOR-swizzled; double-buffered, counted vmcnt (proven rounds 1/3/5/6/8).
#define BM 128
#define BN 128
#define BKG 64

__global__ __launch_bounds__(256) void gemm_bt(
    const short* __restrict__ A, const short* __restrict__ Bt, void* __restrict__ C,
    const float* __restrict__ bias, int M, int N, int Kd,
    int lda, int ldb, int ldc, long sA, long sB, long sC, float scale, int epi,
    int ksplit)
{
    __shared__ short lA[2][BM * BKG];
    __shared__ short lB[2][BN * BKG];
    const int tid = threadIdx.x;
    const int wave = tid >> 6, lane = tid & 63;
    const int wy = wave >> 1, wx = wave & 1;
    const int lr = lane & 15, quad = lane >> 4;
    int bx = blockIdx.x, by = blockIdx.y;
    xcd_swizzle(bx, by);
    const int m0 = by * BM, n0 = bx * BN;
    const int z = blockIdx.z;
    const short* Ab = A + (size_t)z * sA;
    const short* Bb = Bt + (size_t)z * sB;

    f32x4 acc[4][4];
#pragma unroll
    for (int i = 0; i < 4; i++)
#pragma unroll
        for (int j = 0; j < 4; j++) acc[i][j] = (f32x4){0.f, 0.f, 0.f, 0.f};

    const int sRow = lane >> 3;                       // 0..7
    const int sCol = (((lane & 7) ^ sRow) << 3);      // swizzled chunk * 8 shorts

    int kbeg = 0, kend = Kd;
    if (ksplit > 1) { const int kc = Kd / ksplit; kbeg = z * kc; kend = kbeg + kc; }
    const int nsteps = (kend - kbeg) / BKG;

    auto stage = [&](int buf, int k0) {
#pragma unroll
        for (int n = 0; n < 4; ++n) {
            const int c = wave * 4 + n;
            int ar = m0 + c * 8 + sRow; if (ar > M - 1) ar = M - 1;
            load_lds16(Ab + (size_t)ar * lda + k0 + sCol, &lA[buf][c * 512]);
            int br = n0 + c * 8 + sRow; if (br > N - 1) br = N - 1;
            load_lds16(Bb + (size_t)br * ldb + k0 + sCol, &lB[buf][c * 512]);
        }
    };

    stage(0, kbeg);
    for (int t = 0; t < nsteps; ++t) {
        const int cur = t & 1;
        if (t + 1 < nsteps) {
            stage(cur ^ 1, kbeg + (t + 1) * BKG);
            asm volatile("s_waitcnt vmcnt(8)\n\ts_barrier" ::: "memory");
        } else {
            asm volatile("s_waitcnt vmcnt(0)\n\ts_barrier" ::: "memory");
        }
#pragma unroll
        for (int kk = 0; kk < BKG; kk += 32) {
            const int k4 = kk >> 3;                   // 0 or 4
            bf16x8 av[4], bv[4];
#pragma unroll
            for (int i = 0; i < 4; i++) {
                const int ri = wy * 64 + i * 16 + lr;
                av[i] = *(const bf16x8*)&lA[cur][ri * BKG + ((((k4 + quad) ^ (ri & 7)) << 3))];
            }
#pragma unroll
            for (int j = 0; j < 4; j++) {
                const int rj = wx * 64 + j * 16 + lr;
                bv[j] = *(const bf16x8*)&lB[cur][rj * BKG + ((((k4 + quad) ^ (rj & 7)) << 3))];
            }
#pragma unroll
            for (int i = 0; i < 4; i++)
#pragma unroll
                for (int j = 0; j < 4; j++)
                    acc[i][j] = __builtin_amdgcn_mfma_f32_16x16x32_bf16(av[i], bv[j], acc[i][j], 0, 0, 0);
        }
        asm volatile("s_barrier" ::: "memory");
    }

    const int colBase = n0 + wx * 64 + lr;
    if (epi == 3) {
        float* Cp = (float*)C + (size_t)z * sC;
#pragma unroll
        for (int i = 0; i < 4; i++) {
            const int row0 = m0 + wy * 64 + i * 16 + quad * 4;
#pragma unroll
            for (int j = 0; j < 4; j++) {
                const int col = colBase + j * 16;
                if (col >= N) continue;
                const float bv_ = bias ? bias[col] : 0.f;
#pragma unroll
                for (int r = 0; r < 4; r++) {
                    const int row = row0 + r;
                    if (row < M) Cp[(size_t)row * ldc + col] += acc[i][j][r] + bv_;
                }
            }
        }
    } else {
        __hip_bfloat16* Cp = (__hip_bfloat16*)C + (size_t)z * sC;
#pragma unroll
        for (int i = 0; i < 4; i++) {
            const int row0 = m0 + wy * 64 + i * 16 + quad * 4;
#pragma unroll
            for (int j = 0; j < 4; j++) {
                const int col = colBase + j * 16;
                if (col >= N) continue;
                const float bv_ = (epi == 1) ? bias[col] : 0.f;
#pragma unroll
                for (int r = 0; r < 4; r++) {
                    const int row = row0 + r;
                    if (row < M) {
                        float v = acc[i][j][r];
                        if (epi == 1) { v += bv_; v = v > 0.f ? v : 0.f; }
                        else if (epi == 2) v *= scale;
                        Cp[(size_t)row * ldc + col] = __float2bfloat16(v);
                    }
                }
            }
        }
    }
}

// ---------------- fused flash attention, branch A v2 (round-8 verified, 142 us) ----------------
// 256 threads / 4 waves; 64 q-rows per block (16/wave); KV tiles of 64 keys.
// LDS 72 KB -> 2 blocks/CU (grid 528 ~ 2.06/CU for TLP latency hiding).
// Sync: plain __syncthreads() only (spill-proof). 2 barriers/tile: pbuf is
// wave-private (same-wave RAW handled by compiler lgkmcnt).
// Block map: id&7 = XCD chunk (2 batches/XCD = 4MB = L2); heavy-first mt order.
// Causal: mt=0 (cache rows) -> 32 tiles; mt>=1 -> mt tiles.
// NOTE (r9 lesson): larger per-wave row counts (32 rows/wave, grid 272) drop to
// ~1 blk/CU and regress 142->242 us despite halving LDS reads/MFMA. Keep >=528 blocks.
__global__ __launch_bounds__(256, 2) void flash_a(
    const short* __restrict__ q,    // [B*CL][512], q_a = cols 0..255
    const short* __restrict__ ka,   // [B][2048][256]
    const short* __restrict__ vt,   // [B][256][2048]
    short* __restrict__ out)        // hnat [B*CL][CD], writes cols 0..255
{
    __shared__ short kbuf[64 * 256];    // 32 KB, [key][dh], 32 chunks/row, phys c holds logical c^(r&7)
    __shared__ short vbuf[256 * 64];    // 32 KB, [dh][key],  8 chunks/row
    __shared__ short pbuf[64 * 64];     //  8 KB, [qrow][key], wave-private rows
    const int tid = threadIdx.x, wave = tid >> 6, lane = tid & 63;
    const int lr = lane & 15, quad = lane >> 4;

    // block id -> (batch, m-tile): XCD chunk = id&7 covers batches 2x,2x+1;
    // within chunk, heavy-first (mt=0 [32 tiles], then mt=32,31,...,1).
    const int id = blockIdx.x;
    const int x = id & 7, k = id >> 3;          // k in 0..65
    const int b = 2 * x + (k >= 33);
    const int mi = (k >= 33) ? (k - 33) : k;    // 0..32
    const int mt = (mi == 0) ? 0 : (33 - mi);
    const int m0 = mt * 64;
    const short* kab = ka + (size_t)b * 2048 * 256;
    const short* vtb = vt + (size_t)b * 256 * 2048;

    const int nkt = (mt == 0) ? 32 : mt;

    // ---- Q A-fragments in registers (16 rows/wave, reused across all K-tiles) ----
    bf16x8 qf[8];
    {
        const int qr = m0 + wave * 16 + lr;     // < CL always (CL = 33*64)
        const short* p0 = q + ((size_t)b * CL + qr) * 512;
#pragma unroll
        for (int s = 0; s < 8; ++s) qf[s] = *(const bf16x8*)(p0 + s * 32 + quad * 8);
    }

    // stage K tile kt: 2048 chunks of 16B, linear LDS dest, pre-swizzled global src
    auto stageK = [&](int kt) {
#pragma unroll
        for (int u = 0; u < 8; ++u) {
            const int seg = u * 4 + wave;             // 0..31
            const int idx = seg * 64 + lane;          // chunk 0..2047
            const int row = idx >> 5, cp = idx & 31;
            const int cs = cp ^ (row & 7);
            load_lds16(kab + (size_t)(kt * 64 + row) * 256 + cs * 8, kbuf + seg * 512);
        }
    };
    auto stageV = [&](int kt) {
#pragma unroll
        for (int u = 0; u < 8; ++u) {
            const int seg = u * 4 + wave;
            const int idx = seg * 64 + lane;
            const int row = idx >> 3, cp = idx & 7;   // row = dh 0..255
            const int cs = cp ^ (row & 7);
            load_lds16(vtb + (size_t)row * 2048 + kt * 64 + cs * 8, vbuf + seg * 512);
        }
    };

    f32x4 acc_o[16];
#pragma unroll
    for (int jd = 0; jd < 16; jd++) acc_o[jd] = (f32x4){0.f, 0.f, 0.f, 0.f};
    float m_run[4], l_run[4];
    int limit[4];
#pragma unroll
    for (int rr = 0; rr < 4; rr++) {
        m_run[rr] = -1e30f; l_run[rr] = 0.f;
        const int trow = m0 + wave * 16 + quad * 4 + rr;
        limit[rr] = (trow < CK) ? CW : (trow - (CK - 1));
    }

    for (int kt = 0; kt < nkt; ++kt) {
        stageK(kt);
        stageV(kt);
        __syncthreads();                 // staging resident (vmcnt(0)+barrier)

        // ---- QK^T: S[16 x 64] per wave ----
        f32x4 s_[4];
#pragma unroll
        for (int j = 0; j < 4; j++) s_[j] = (f32x4){0.f, 0.f, 0.f, 0.f};
#pragma unroll
        for (int s = 0; s < 8; ++s) {
#pragma unroll
            for (int j = 0; j < 4; ++j) {
                const int rj = j * 16 + lr;
                const bf16x8 bv = *(const bf16x8*)&kbuf[rj * 256 + (((s * 4 + quad) ^ (rj & 7)) << 3)];
                s_[j] = __builtin_amdgcn_mfma_f32_16x16x32_bf16(qf[s], bv, s_[j], 0, 0, 0);
            }
        }

        // ---- mask + online softmax (row = wave*16 + quad*4 + rr, cols over lr,j) ----
        const int kbase = kt * 64;
        float tmax[4];
#pragma unroll
        for (int rr = 0; rr < 4; rr++) tmax[rr] = -1e30f;
#pragma unroll
        for (int j = 0; j < 4; j++) {
            const int key = kbase + j * 16 + lr;
#pragma unroll
            for (int rr = 0; rr < 4; rr++) {
                const float v = (key < limit[rr]) ? s_[j][rr] * 0.0625f : -1e30f;
                s_[j][rr] = v;
                tmax[rr] = fmaxf(tmax[rr], v);
            }
        }
#pragma unroll
        for (int rr = 0; rr < 4; rr++) {
#pragma unroll
            for (int off = 1; off < 16; off <<= 1)
                tmax[rr] = fmaxf(tmax[rr], __shfl_xor(tmax[rr], off));
        }
        float scal[4], rowsum[4];
#pragma unroll
        for (int rr = 0; rr < 4; rr++) {
            const float mn = fmaxf(m_run[rr], tmax[rr]);
            scal[rr] = __expf(m_run[rr] - mn);
            m_run[rr] = mn;
            rowsum[rr] = 0.f;
        }
        // P = exp(S - m) -> bf16, lane-pair packed b32 writes into swizzled pbuf
#pragma unroll
        for (int j = 0; j < 4; j++) {
            const int cch = j * 2 + (lr >> 3);        // col chunk 0..7
#pragma unroll
            for (int rr = 0; rr < 4; rr++) {
                const float e = __expf(s_[j][rr] - m_run[rr]);
                rowsum[rr] += e;
                const float eo = __shfl_xor(e, 1);
                const __hip_bfloat16 b0 = __float2bfloat16(e);
                const __hip_bfloat16 b1 = __float2bfloat16(eo);
                const unsigned pk = ((unsigned)(*(const unsigned short*)&b1) << 16)
                                  | (unsigned)(*(const unsigned short*)&b0);
                if (!(lane & 1)) {
                    const int prow = wave * 16 + quad * 4 + rr;   // local 0..63
                    *(unsigned*)&pbuf[prow * 64 + ((cch ^ (prow & 7)) << 3) + (lr & 6)] = pk;
                }
            }
        }
#pragma unroll
        for (int rr = 0; rr < 4; rr++) {
#pragma unroll
            for (int off = 1; off < 16; off <<= 1)
                rowsum[rr] += __shfl_xor(rowsum[rr], off);
            l_run[rr] = l_run[rr] * scal[rr] + rowsum[rr];
        }
#pragma unroll
        for (int jd = 0; jd < 16; jd++)
#pragma unroll
            for (int rr = 0; rr < 4; rr++) acc_o[jd][rr] *= scal[rr];

        // (no barrier: pbuf rows are wave-private; compiler orders same-wave LDS ops)

        // ---- PV: O[16 x 256] += P[16 x 64] @ V^T ----
        const int pr = wave * 16 + lr;
#pragma unroll
        for (int s2 = 0; s2 < 2; ++s2) {
            const bf16x8 pa = *(const bf16x8*)&pbuf[pr * 64 + (((s2 * 4 + quad) ^ (pr & 7)) << 3)];
#pragma unroll
            for (int jd = 0; jd < 16; ++jd) {
                const int rj = jd * 16 + lr;
                const bf16x8 bv = *(const bf16x8*)&vbuf[rj * 64 + (((s2 * 4 + quad) ^ (rj & 7)) << 3)];
                acc_o[jd] = __builtin_amdgcn_mfma_f32_16x16x32_bf16(pa, bv, acc_o[jd], 0, 0, 0);
            }
        }
        __syncthreads();                 // all kbuf/vbuf reads done before next staging
    }

    // ---- epilogue: O / l -> bf16, cols 0..255 of out ----
#pragma unroll
    for (int rr = 0; rr < 4; rr++) {
        const int trow = m0 + wave * 16 + quad * 4 + rr;
        const float rinv = 1.f / l_run[rr];
        __hip_bfloat16* op = (__hip_bfloat16*)out + ((size_t)b * CL + trow) * CD;
#pragma unroll
        for (int jd = 0; jd < 16; jd++)
            op[jd * 16 + lr] = __float2bfloat16(acc_o[jd][rr] * rinv);
    }
}

// ---------------- embedding ----------------
__global__ void embed_kernel(const int* __restrict__ cache, const int* __restrict__ seq,
                             const float* __restrict__ item, const float* __restrict__ cpos,
                             const float* __restrict__ spos, const float* __restrict__ seg,
                             float* __restrict__ h)
{
    const int row = blockIdx.x;
    const int b = row / CL, t = row - b * CL;
    const int d = threadIdx.x * 4;
    int id; const float* pos; const float* sg;
    if (t < CK) { id = cache[b * CK + t]; pos = cpos + (size_t)t * CD; sg = seg; }
    else { const int tt = t - CK; id = seq[b * CW + tt]; pos = spos + (size_t)tt * CD; sg = seg + CD; }
    const float4 ev = *(const float4*)(item + (size_t)id * CD + d);
    const float4 pv = *(const float4*)(pos + d);
    const float4 sv = *(const float4*)(sg + d);
    float4 r; r.x = ev.x + pv.x + sv.x; r.y = ev.y + pv.y + sv.y;
    r.z = ev.z + pv.z + sv.z; r.w = ev.w + pv.w + sv.w;
    *(float4*)(h + (size_t)row * CD + d) = r;
}

// ---------------- layernorm -> bf16, wave-per-row (no LDS, no barriers) ----------------
// 4 rows per 256-thread block; each wave reduces its own 512-float row via
// __shfl_xor only; 32 B/lane loads, 16 B/lane store.
__global__ __launch_bounds__(256) void ln_kernel(const float* __restrict__ h, const float* __restrict__ g,
                                                 const float* __restrict__ bb, __hip_bfloat16* __restrict__ out)
{
    const int row = blockIdx.x * 4 + (threadIdx.x >> 6);
    const int lane = threadIdx.x & 63;
    const float* x = h + (size_t)row * CD + lane * 8;
    const float4 a = *(const float4*)(x);
    const float4 c = *(const float4*)(x + 4);
    float s  = a.x + a.y + a.z + a.w + c.x + c.y + c.z + c.w;
    float s2 = a.x*a.x + a.y*a.y + a.z*a.z + a.w*a.w
             + c.x*c.x + c.y*c.y + c.z*c.z + c.w*c.w;
#pragma unroll
    for (int off = 32; off; off >>= 1) {
        s  += __shfl_xor(s, off);
        s2 += __shfl_xor(s2, off);
    }
    const float mu = s * (1.f / CD);
    const float var = s2 * (1.f / CD) - mu * mu;
    const float rs = rsqrtf(var + 1e-5f);
    const float4 g0 = *(const float4*)(g + lane * 8);
    const float4 g1 = *(const float4*)(g + lane * 8 + 4);
    const float4 b0 = *(const float4*)(bb + lane * 8);
    const float4 b1 = *(const float4*)(bb + lane * 8 + 4);
    float v[8] = { (a.x-mu)*rs*g0.x + b0.x, (a.y-mu)*rs*g0.y + b0.y,
                   (a.z-mu)*rs*g0.z + b0.z, (a.w-mu)*rs*g0.w + b0.w,
                   (c.x-mu)*rs*g1.x + b1.x, (c.y-mu)*rs*g1.y + b1.y,
                   (c.z-mu)*rs*g1.z + b1.z, (c.w-mu)*rs*g1.w + b1.w };
    bf16x8 ov;
#pragma unroll
    for (int kk = 0; kk < 8; kk++) {
        const __hip_bfloat16 hb = __float2bfloat16(v[kk]);
        ov[kk] = *(const short*)&hb;
    }
    *(bf16x8*)(out + (size_t)row * CD + lane * 8) = ov;
}

// ---------------- softmax over 64 (branch B), wave per row ----------------
__global__ __launch_bounds__(256) void softmax_b_kernel(__hip_bfloat16* __restrict__ sb)
{
    const int row = blockIdx.x * 4 + (threadIdx.x >> 6);
    const int lane = threadIdx.x & 63;
    __hip_bfloat16* pr = sb + (size_t)row * 64;
    float x = __bfloat162float(pr[lane]);
    float m = x;
#pragma unroll
    for (int off = 32; off; off >>= 1) m = fmaxf(m, __shfl_xor(m, off));
    const float e = __expf(x - m);
    float s = e;
#pragma unroll
    for (int off = 32; off; off >>= 1) s += __shfl_xor(s, off);
    pr[lane] = __float2bfloat16(e / s);
}

// ---------------- final LN + logits ----------------
__global__ __launch_bounds__(256) void final_kernel(const float* __restrict__ h, const float* __restrict__ g,
                                                    const float* __restrict__ bb, const float* __restrict__ wev,
                                                    const float* __restrict__ bev, float* __restrict__ out)
{
    const int idx = blockIdx.x;
    const int b = idx >> 6, t = idx & 63;
    const float* x = h + ((size_t)b * CL + t) * CD;
    const int tid = threadIdx.x, wv = tid >> 6, lane = tid & 63;
    const float2 v = *(const float2*)(x + tid * 2);
    float s = v.x + v.y, s2 = v.x * v.x + v.y * v.y;
    __shared__ float red[8];
#pragma unroll
    for (int off = 32; off; off >>= 1) { s += __shfl_down(s, off); s2 += __shfl_down(s2, off); }
    if (lane == 0) { red[wv] = s; red[4 + wv] = s2; }
    __syncthreads();
    s = red[0] + red[1] + red[2] + red[3];
    s2 = red[4] + red[5] + red[6] + red[7];
    const float mu = s * (1.f / CD);
    const float var = s2 * (1.f / CD) - mu * mu;
    const float rs = rsqrtf(var + 1e-5f);
    const float2 gg = *(const float2*)(g + tid * 2);
    const float2 bv = *(const float2*)(bb + tid * 2);
    const float2 wv2 = *(const float2*)(wev + tid * 2);
    float val = ((v.x - mu) * rs * gg.x + bv.x) * wv2.x + ((v.y - mu) * rs * gg.y + bv.y) * wv2.y;
#pragma unroll
    for (int off = 32; off; off >>= 1) val += __shfl_down(val, off);
    __syncthreads();
    if (lane == 0) red[wv] = val;
    __syncthreads();
    if (tid == 0) out[idx] = red[0] + red[1] + red[2] + red[3] + bev[0];
}

// ---------------- transpose-convert: fp32 [z][R][C] -> bf16 [z][C][R] ----------------
__global__ void transpose_f32(const float* __restrict__ in, __hip_bfloat16* __restrict__ out,
                              int R, int Cc, long inzs, long outzs)
{
    __shared__ float tile[32][33];
    const size_t zi = (size_t)blockIdx.z * inzs;
    const size_t zo = (size_t)blockIdx.z * outzs;
    const int c0 = blockIdx.x * 32, r0 = blockIdx.y * 32;
    const int tx = threadIdx.x, ty = threadIdx.y;
#pragma unroll
    for (int i = ty; i < 32; i += 8)
        tile[i][tx] = in[zi + (size_t)(r0 + i) * Cc + c0 + tx];
    __syncthreads();
#pragma unroll
    for (int i = ty; i < 32; i += 8)
        out[zo + (size_t)(c0 + i) * R + r0 + tx] = __float2bfloat16(tile[tx][i]);
}

extern "C" void kernel_launch(void* const* d_in, const int* in_sizes, int n_in,
                              void* d_out, int out_size, void* d_ws, size_t ws_size,
                              hipStream_t stream)
{
    const int*   cache = (const int*)d_in[0];
    const int*   seq   = (const int*)d_in[1];
    const float* item  = (const float*)d_in[2];
    const float* cpos  = (const float*)d_in[3];
    const float* spos  = (const float*)d_in[4];
    const float* seg   = (const float*)d_in[5];
    const float* wq_s  = (const float*)d_in[6];
    const float* wk_s  = (const float*)d_in[7];
    const float* wv_s  = (const float*)d_in[8];
    const float* wq_c  = (const float*)d_in[9];
    const float* wk_c  = (const float*)d_in[10];
    const float* wv_c  = (const float*)d_in[11];
    const float* w_out = (const float*)d_in[12];
    const float* b_out = (const float*)d_in[13];
    const float* ln1_g = (const float*)d_in[14];
    const float* ln1_b = (const float*)d_in[15];
    const float* ln2_g = (const float*)d_in[16];
    const float* ln2_b = (const float*)d_in[17];
    const float* w_ff1 = (const float*)d_in[18];
    const float* b_ff1 = (const float*)d_in[19];
    const float* w_ff2 = (const float*)d_in[20];
    const float* b_ff2 = (const float*)d_in[21];
    const float* fin_g = (const float*)d_in[22];
    const float* fin_b = (const float*)d_in[23];
    const float* w_ev  = (const float*)d_in[24];
    const float* b_ev  = (const float*)d_in[25];

    // ---- workspace layout (~237 MiB) ----
    char* p = (char*)d_ws;
    auto alloc = [&](size_t bytes) { char* r = p; p += (bytes + 255) & ~(size_t)255; return (void*)r; };
    float* h    = (float*)alloc((size_t)CROWS * CD * 4);           // 69.2 MB
    short* hnat = (short*)alloc((size_t)CROWS * CD * 2);           // 34.6 MB  (hn, later attn)
    short* q    = (short*)alloc((size_t)CROWS * 512 * 2);          // 34.6 MB  (q_a | q_b)
    short* ka   = (short*)alloc((size_t)CB * CW * CDH * 2);        // 16.8 MB
    short* vt   = (short*)alloc((size_t)CB * CDH * CW * 2);        // 16.8 MB
    short* kb   = (short*)alloc((size_t)CB * 64 * CDH * 2);        // 0.5 MB
    short* vbT  = (short*)alloc((size_t)CB * CDH * 64 * 2);        // 0.5 MB
    short* sb   = (short*)alloc((size_t)CB * CL * 64 * 2);         // 4.3 MB
    short* big  = (short*)alloc((size_t)4 * CL * CW * 2);          // 34.6 MB (spare)
    short* wqT  = (short*)alloc((size_t)CNL * 512 * CD * 2);       // 2.1 MB
    short* wksT = (short*)alloc((size_t)CNL * CDH * CD * 2);
    short* wvsT = (short*)alloc((size_t)CNL * CDH * CD * 2);
    short* wkcT = (short*)alloc((size_t)CNL * CDH * CD * 2);
    short* wvcT = (short*)alloc((size_t)CNL * CDH * CD * 2);
    short* woT  = (short*)alloc((size_t)CNL * CD * CD * 2);
    short* wf1T = (short*)alloc((size_t)CNL * CDFF * CD * 2);
    short* wf2T = (short*)alloc((size_t)CNL * CD * CDFF * 2);
    // FFN intermediate (16896 x 2048 bf16 = 69.2 MB) aliases q..sb (~73.5 MB),
    // all dead during the FFN phase (recomputed every layer from hnat).
    short* ffbig = q;
    (void)big;

    const dim3 tb(32, 8);
    const long zqk = (long)CD * CDH;      // 131072
    const long zqT = (long)512 * CD;      // 262144
    transpose_f32<<<dim3(CDH/32, CD/32, CNL), tb, 0, stream>>>(wq_s, (__hip_bfloat16*)wqT, CD, CDH, zqk, zqT);
    transpose_f32<<<dim3(CDH/32, CD/32, CNL), tb, 0, stream>>>(wq_c, (__hip_bfloat16*)(wqT + (size_t)CDH * CD), CD, CDH, zqk, zqT);
    transpose_f32<<<dim3(CDH/32, CD/32, CNL), tb, 0, stream>>>(wk_s, (__hip_bfloat16*)wksT, CD, CDH, zqk, zqk);
    transpose_f32<<<dim3(CDH/32, CD/32, CNL), tb, 0, stream>>>(wv_s, (__hip_bfloat16*)wvsT, CD, CDH, zqk, zqk);
    transpose_f32<<<dim3(CDH/32, CD/32, CNL), tb, 0, stream>>>(wk_c, (__hip_bfloat16*)wkcT, CD, CDH, zqk, zqk);
    transpose_f32<<<dim3(CDH/32, CD/32, CNL), tb, 0, stream>>>(wv_c, (__hip_bfloat16*)wvcT, CD, CDH, zqk, zqk);
    transpose_f32<<<dim3(CD/32, CD/32, CNL), tb, 0, stream>>>(w_out, (__hip_bfloat16*)woT, CD, CD, (long)CD*CD, (long)CD*CD);
    transpose_f32<<<dim3(CDFF/32, CD/32, CNL), tb, 0, stream>>>(w_ff1, (__hip_bfloat16*)wf1T, CD, CDFF, (long)CD*CDFF, (long)CD*CDFF);
    transpose_f32<<<dim3(CD/32, CDFF/32, CNL), tb, 0, stream>>>(w_ff2, (__hip_bfloat16*)wf2T, CDFF, CD, (long)CD*CDFF, (long)CD*CDFF);

    embed_kernel<<<CROWS, 128, 0, stream>>>(cache, seq, item, cpos, spos, seg, h);

    const int mtilesR = CROWS / 128;          // 264
    const int mtilesL = (CL + 127) / 128;     // 17

    for (int l = 0; l < CNL; ++l) {
        const short* wqTl  = wqT  + (size_t)l * 512 * CD;
        const short* wksTl = wksT + (size_t)l * CDH * CD;
        const short* wvsTl = wvsT + (size_t)l * CDH * CD;
        const short* wkcTl = wkcT + (size_t)l * CDH * CD;
        const short* wvcTl = wvcT + (size_t)l * CDH * CD;
        const short* woTl  = woT  + (size_t)l * CD * CD;
        const short* wf1Tl = wf1T + (size_t)l * CDFF * CD;
        const short* wf2Tl = wf2T + (size_t)l * CD * CDFF;

        ln_kernel<<<CROWS / 4, 256, 0, stream>>>(h, ln1_g + l * CD, ln1_b + l * CD, (__hip_bfloat16*)hnat);

        // q = hn @ [wq_s | wq_c]   (CROWS x 512)
        gemm_bt<<<dim3(512/128, mtilesR, 1), 256, 0, stream>>>(hnat, wqTl, q, nullptr,
            CROWS, 512, CD, CD, CD, 512, 0, 0, 0, 1.f, 0, 1);
        // k_a from hn_seq (batched over 16)
        gemm_bt<<<dim3(CDH/128, CW/128, CB), 256, 0, stream>>>(hnat + (size_t)CK * CD, wksTl, ka, nullptr,
            CW, CDH, CD, CD, CD, CDH, (long)CL * CD, 0, (long)CW * CDH, 1.f, 0, 1);
        // k_b  (M=64, N=256)
        gemm_bt<<<dim3(CDH/128, 1, CB), 256, 0, stream>>>(hnat, wkcTl, kb, nullptr,
            64, CDH, CD, CD, CD, CDH, (long)CL * CD, 0, (long)64 * CDH, 1.f, 0, 1);
        // vbT[d][key] = v_b^T  (M=256, N=64)
        gemm_bt<<<dim3(1, CDH/128, CB), 256, 0, stream>>>(wvcTl, hnat, vbT, nullptr,
            CDH, 64, CD, CD, CD, 64, 0, (long)CL * CD, (long)CDH * 64, 1.f, 0, 1);
        // vt[d][w] = v_a^T  (M=256, N=2048)
        gemm_bt<<<dim3(CW/128, CDH/128, CB), 256, 0, stream>>>(wvsTl, hnat + (size_t)CK * CD, vt, nullptr,
            CDH, CW, CD, CD, CD, CW, 0, (long)CL * CD, (long)CDH * CW, 1.f, 0, 1);

        // ---- branch B: scores_b = (q_b @ k_b^T)*scale -> softmax64 -> @ v_b ----
        gemm_bt<<<dim3(1, mtilesL, CB), 256, 0, stream>>>(q + CDH, kb, sb, nullptr,
            CL, 64, CDH, 512, CDH, 64, (long)CL * 512, (long)64 * CDH, (long)CL * 64, 0.0625f, 2, 1);
        softmax_b_kernel<<<(CB * CL) / 4, 256, 0, stream>>>((__hip_bfloat16*)sb);
        gemm_bt<<<dim3(CDH/128, mtilesL, CB), 256, 0, stream>>>(sb, vbT, hnat + CDH, nullptr,
            CL, CDH, 64, 64, 64, CD, (long)CL * 64, (long)CDH * 64, (long)CL * CD, 1.f, 0, 1);

        // ---- branch A: fused flash attention -> hnat cols [0,256) ----
        flash_a<<<dim3(528), 256, 0, stream>>>(q, ka, vt, hnat);

        // h += attn @ w_out + b_out
        gemm_bt<<<dim3(CD/128, mtilesR, 1), 256, 0, stream>>>(hnat, woTl, h, b_out + l * CD,
            CROWS, CD, CD, CD, CD, CD, 0, 0, 0, 1.f, 3, 1);

        ln_kernel<<<CROWS / 4, 256, 0, stream>>>(h, ln2_g + l * CD, ln2_b + l * CD, (__hip_bfloat16*)hnat);

        // FFN in 2 row chunks; intermediate aliases dead q..sb region.
        for (int c = 0; c < NCH; ++c) {
            const size_t r0 = (size_t)c * RCH2;
            gemm_bt<<<dim3(CDFF/128, RCH2/128, 1), 256, 0, stream>>>(hnat + r0 * CD, wf1Tl, ffbig, b_ff1 + l * CDFF,
                RCH2, CDFF, CD, CD, CD, CDFF, 0, 0, 0, 1.f, 1, 1);
            gemm_bt<<<dim3(CD/128, RCH2/128, 1), 256, 0, stream>>>(ffbig, wf2Tl, h + r0 * CD, b_ff2 + l * CD,
                RCH2, CD, CDFF, CDFF, CDFF, CD, 0, 0, 0, 1.f, 3, 1);
        }
    }

    final_kernel<<<CB * CK, 256, 0, stream>>>(h, fin_g, fin_b, w_ev, b_ev, (float*)d_out);
}

// Round 11
// 3302.875 us; speedup vs baseline: 1.1587x; 1.0132x over previous
//
#include <hip/hip_runtime.h>
#include <hip/hip_bf16.h>
#include <cstdint>

#define CB 16
#define CK 64
#define CW 2048
#define CL 2112
#define CD 512
#define CDH 256
#define CDFF 2048
#define CNL 4
#define CROWS (CB*CL)
#define NCH 2                // FFN row chunks
#define RCH2 (CROWS/NCH)     // 16896 = 132*128

typedef __attribute__((ext_vector_type(8))) short bf16x8;
typedef __attribute__((ext_vector_type(4))) float f32x4;

__device__ __forceinline__ float bf2f(unsigned short u) {
    union { unsigned int i; float f; } x; x.i = ((unsigned int)u) << 16; return x.f;
}

__device__ __forceinline__ void load_lds16(const void* g, void* l) {
    __builtin_amdgcn_global_load_lds(
        (const __attribute__((address_space(1))) void*)g,
        (__attribute__((address_space(3))) void*)l, 16, 0, 0);
}

// XCD-aware bijective block swizzle (m204): only applied when nwg%8==0.
__device__ __forceinline__ void xcd_swizzle(int& bx, int& by) {
    const int gx = gridDim.x, nwg = gx * gridDim.y;
    if ((nwg & 7) == 0) {
        const int flat = by * gx + bx;
        const int cpx = nwg >> 3;
        const int swz = (flat & 7) * cpx + (flat >> 3);
        bx = swz % gx; by = swz / gx;
    }
}

// ---------------- GEMM 128x128: C[MxN] = A[MxK] @ Bt[NxK]^T, bf16 in, fp32 acc ----------------
// epi 0: C bf16 = acc ; epi 1: bf16 relu(acc+bias) ; epi 2: bf16 acc*scale ; epi 3: fp32 C += acc+bias
// LDS XOR-swizzled; double-buffered, counted vmcnt (proven rounds 1/3/5/6/8/10).
#define BM 128
#define BN 128
#define BKG 64

__global__ __launch_bounds__(256) void gemm_bt(
    const short* __restrict__ A, const short* __restrict__ Bt, void* __restrict__ C,
    const float* __restrict__ bias, int M, int N, int Kd,
    int lda, int ldb, int ldc, long sA, long sB, long sC, float scale, int epi,
    int ksplit)
{
    __shared__ short lA[2][BM * BKG];
    __shared__ short lB[2][BN * BKG];
    const int tid = threadIdx.x;
    const int wave = tid >> 6, lane = tid & 63;
    const int wy = wave >> 1, wx = wave & 1;
    const int lr = lane & 15, quad = lane >> 4;
    int bx = blockIdx.x, by = blockIdx.y;
    xcd_swizzle(bx, by);
    const int m0 = by * BM, n0 = bx * BN;
    const int z = blockIdx.z;
    const short* Ab = A + (size_t)z * sA;
    const short* Bb = Bt + (size_t)z * sB;

    f32x4 acc[4][4];
#pragma unroll
    for (int i = 0; i < 4; i++)
#pragma unroll
        for (int j = 0; j < 4; j++) acc[i][j] = (f32x4){0.f, 0.f, 0.f, 0.f};

    const int sRow = lane >> 3;                       // 0..7
    const int sCol = (((lane & 7) ^ sRow) << 3);      // swizzled chunk * 8 shorts

    int kbeg = 0, kend = Kd;
    if (ksplit > 1) { const int kc = Kd / ksplit; kbeg = z * kc; kend = kbeg + kc; }
    const int nsteps = (kend - kbeg) / BKG;

    auto stage = [&](int buf, int k0) {
#pragma unroll
        for (int n = 0; n < 4; ++n) {
            const int c = wave * 4 + n;
            int ar = m0 + c * 8 + sRow; if (ar > M - 1) ar = M - 1;
            load_lds16(Ab + (size_t)ar * lda + k0 + sCol, &lA[buf][c * 512]);
            int br = n0 + c * 8 + sRow; if (br > N - 1) br = N - 1;
            load_lds16(Bb + (size_t)br * ldb + k0 + sCol, &lB[buf][c * 512]);
        }
    };

    stage(0, kbeg);
    for (int t = 0; t < nsteps; ++t) {
        const int cur = t & 1;
        if (t + 1 < nsteps) {
            stage(cur ^ 1, kbeg + (t + 1) * BKG);
            asm volatile("s_waitcnt vmcnt(8)\n\ts_barrier" ::: "memory");
        } else {
            asm volatile("s_waitcnt vmcnt(0)\n\ts_barrier" ::: "memory");
        }
#pragma unroll
        for (int kk = 0; kk < BKG; kk += 32) {
            const int k4 = kk >> 3;                   // 0 or 4
            bf16x8 av[4], bv[4];
#pragma unroll
            for (int i = 0; i < 4; i++) {
                const int ri = wy * 64 + i * 16 + lr;
                av[i] = *(const bf16x8*)&lA[cur][ri * BKG + ((((k4 + quad) ^ (ri & 7)) << 3))];
            }
#pragma unroll
            for (int j = 0; j < 4; j++) {
                const int rj = wx * 64 + j * 16 + lr;
                bv[j] = *(const bf16x8*)&lB[cur][rj * BKG + ((((k4 + quad) ^ (rj & 7)) << 3))];
            }
#pragma unroll
            for (int i = 0; i < 4; i++)
#pragma unroll
                for (int j = 0; j < 4; j++)
                    acc[i][j] = __builtin_amdgcn_mfma_f32_16x16x32_bf16(av[i], bv[j], acc[i][j], 0, 0, 0);
        }
        asm volatile("s_barrier" ::: "memory");
    }

    const int colBase = n0 + wx * 64 + lr;
    if (epi == 3) {
        float* Cp = (float*)C + (size_t)z * sC;
#pragma unroll
        for (int i = 0; i < 4; i++) {
            const int row0 = m0 + wy * 64 + i * 16 + quad * 4;
#pragma unroll
            for (int j = 0; j < 4; j++) {
                const int col = colBase + j * 16;
                if (col >= N) continue;
                const float bv_ = bias ? bias[col] : 0.f;
#pragma unroll
                for (int r = 0; r < 4; r++) {
                    const int row = row0 + r;
                    if (row < M) Cp[(size_t)row * ldc + col] += acc[i][j][r] + bv_;
                }
            }
        }
    } else {
        __hip_bfloat16* Cp = (__hip_bfloat16*)C + (size_t)z * sC;
#pragma unroll
        for (int i = 0; i < 4; i++) {
            const int row0 = m0 + wy * 64 + i * 16 + quad * 4;
#pragma unroll
            for (int j = 0; j < 4; j++) {
                const int col = colBase + j * 16;
                if (col >= N) continue;
                const float bv_ = (epi == 1) ? bias[col] : 0.f;
#pragma unroll
                for (int r = 0; r < 4; r++) {
                    const int row = row0 + r;
                    if (row < M) {
                        float v = acc[i][j][r];
                        if (epi == 1) { v += bv_; v = v > 0.f ? v : 0.f; }
                        else if (epi == 2) v *= scale;
                        Cp[(size_t)row * ldc + col] = __float2bfloat16(v);
                    }
                }
            }
        }
    }
}

// ---------------- fused flash attention, branches A + B ----------------
// Branch A: v2 structure (round-8/10 verified, 141 us): 256 thr / 4 waves /
// 64 q-rows; KV tiles of 64 keys; LDS 72 KB -> 2 blocks/CU; grid 528;
// plain __syncthreads sync; pbuf wave-private (no softmax->PV barrier).
// Branch B fused: kb [64][256] == K-tile layout, vbT [256][64] == V-tile
// layout -> one extra unmasked tile-step after the A loop, reusing qf/acc_o
// registers; staging overlaps epilogue-A stores; writes out cols 256..511.
// NOTE (r9 lesson): keep >=528 blocks; 32 rows/wave at grid 272 regressed.
__global__ __launch_bounds__(256, 2) void flash_a(
    const short* __restrict__ q,    // [B*CL][512], q_a cols 0..255, q_b cols 256..511
    const short* __restrict__ ka,   // [B][2048][256]
    const short* __restrict__ vt,   // [B][256][2048]
    const short* __restrict__ kb,   // [B][64][256]
    const short* __restrict__ vbT,  // [B][256][64]
    short* __restrict__ out)        // hnat [B*CL][CD], writes cols 0..511
{
    __shared__ short kbuf[64 * 256];    // 32 KB, [key][dh], 32 chunks/row, phys c holds logical c^(r&7)
    __shared__ short vbuf[256 * 64];    // 32 KB, [dh][key],  8 chunks/row
    __shared__ short pbuf[64 * 64];     //  8 KB, [qrow][key], wave-private rows
    const int tid = threadIdx.x, wave = tid >> 6, lane = tid & 63;
    const int lr = lane & 15, quad = lane >> 4;

    // block id -> (batch, m-tile): XCD chunk = id&7 covers batches 2x,2x+1;
    // within chunk, heavy-first (mt=0 [32 tiles], then mt=32,31,...,1).
    const int id = blockIdx.x;
    const int x = id & 7, k = id >> 3;          // k in 0..65
    const int b = 2 * x + (k >= 33);
    const int mi = (k >= 33) ? (k - 33) : k;    // 0..32
    const int mt = (mi == 0) ? 0 : (33 - mi);
    const int m0 = mt * 64;
    const short* kab = ka + (size_t)b * 2048 * 256;
    const short* vtb = vt + (size_t)b * 256 * 2048;
    const short* kbb = kb + (size_t)b * 64 * 256;
    const short* vbb = vbT + (size_t)b * 256 * 64;

    const int nkt = (mt == 0) ? 32 : mt;

    // ---- Q_a A-fragments in registers (16 rows/wave) ----
    bf16x8 qf[8];
    const int qr = m0 + wave * 16 + lr;         // < CL always (CL = 33*64)
    {
        const short* p0 = q + ((size_t)b * CL + qr) * 512;
#pragma unroll
        for (int s = 0; s < 8; ++s) qf[s] = *(const bf16x8*)(p0 + s * 32 + quad * 8);
    }

    // stage K tile kt: 2048 chunks of 16B, linear LDS dest, pre-swizzled global src
    auto stageK = [&](int kt) {
#pragma unroll
        for (int u = 0; u < 8; ++u) {
            const int seg = u * 4 + wave;             // 0..31
            const int idx = seg * 64 + lane;          // chunk 0..2047
            const int row = idx >> 5, cp = idx & 31;
            const int cs = cp ^ (row & 7);
            load_lds16(kab + (size_t)(kt * 64 + row) * 256 + cs * 8, kbuf + seg * 512);
        }
    };
    auto stageV = [&](int kt) {
#pragma unroll
        for (int u = 0; u < 8; ++u) {
            const int seg = u * 4 + wave;
            const int idx = seg * 64 + lane;
            const int row = idx >> 3, cp = idx & 7;   // row = dh 0..255
            const int cs = cp ^ (row & 7);
            load_lds16(vtb + (size_t)row * 2048 + kt * 64 + cs * 8, vbuf + seg * 512);
        }
    };
    // branch-B staging: same shapes, different base/stride
    auto stageKB = [&]() {
#pragma unroll
        for (int u = 0; u < 8; ++u) {
            const int seg = u * 4 + wave;
            const int idx = seg * 64 + lane;
            const int row = idx >> 5, cp = idx & 31;
            const int cs = cp ^ (row & 7);
            load_lds16(kbb + (size_t)row * 256 + cs * 8, kbuf + seg * 512);
        }
    };
    auto stageVB = [&]() {
#pragma unroll
        for (int u = 0; u < 8; ++u) {
            const int seg = u * 4 + wave;
            const int idx = seg * 64 + lane;
            const int row = idx >> 3, cp = idx & 7;   // row = dh 0..255
            const int cs = cp ^ (row & 7);
            load_lds16(vbb + (size_t)row * 64 + cs * 8, vbuf + seg * 512);
        }
    };

    f32x4 acc_o[16];
#pragma unroll
    for (int jd = 0; jd < 16; jd++) acc_o[jd] = (f32x4){0.f, 0.f, 0.f, 0.f};
    float m_run[4], l_run[4];
    int limit[4];
#pragma unroll
    for (int rr = 0; rr < 4; rr++) {
        m_run[rr] = -1e30f; l_run[rr] = 0.f;
        const int trow = m0 + wave * 16 + quad * 4 + rr;
        limit[rr] = (trow < CK) ? CW : (trow - (CK - 1));
    }

    for (int kt = 0; kt < nkt; ++kt) {
        stageK(kt);
        stageV(kt);
        __syncthreads();                 // staging resident (vmcnt(0)+barrier)

        // ---- QK^T: S[16 x 64] per wave ----
        f32x4 s_[4];
#pragma unroll
        for (int j = 0; j < 4; j++) s_[j] = (f32x4){0.f, 0.f, 0.f, 0.f};
#pragma unroll
        for (int s = 0; s < 8; ++s) {
#pragma unroll
            for (int j = 0; j < 4; ++j) {
                const int rj = j * 16 + lr;
                const bf16x8 bv = *(const bf16x8*)&kbuf[rj * 256 + (((s * 4 + quad) ^ (rj & 7)) << 3)];
                s_[j] = __builtin_amdgcn_mfma_f32_16x16x32_bf16(qf[s], bv, s_[j], 0, 0, 0);
            }
        }

        // ---- mask + online softmax (row = wave*16 + quad*4 + rr, cols over lr,j) ----
        const int kbase = kt * 64;
        float tmax[4];
#pragma unroll
        for (int rr = 0; rr < 4; rr++) tmax[rr] = -1e30f;
#pragma unroll
        for (int j = 0; j < 4; j++) {
            const int key = kbase + j * 16 + lr;
#pragma unroll
            for (int rr = 0; rr < 4; rr++) {
                const float v = (key < limit[rr]) ? s_[j][rr] * 0.0625f : -1e30f;
                s_[j][rr] = v;
                tmax[rr] = fmaxf(tmax[rr], v);
            }
        }
#pragma unroll
        for (int rr = 0; rr < 4; rr++) {
#pragma unroll
            for (int off = 1; off < 16; off <<= 1)
                tmax[rr] = fmaxf(tmax[rr], __shfl_xor(tmax[rr], off));
        }
        float scal[4], rowsum[4];
#pragma unroll
        for (int rr = 0; rr < 4; rr++) {
            const float mn = fmaxf(m_run[rr], tmax[rr]);
            scal[rr] = __expf(m_run[rr] - mn);
            m_run[rr] = mn;
            rowsum[rr] = 0.f;
        }
        // P = exp(S - m) -> bf16, lane-pair packed b32 writes into swizzled pbuf
#pragma unroll
        for (int j = 0; j < 4; j++) {
            const int cch = j * 2 + (lr >> 3);        // col chunk 0..7
#pragma unroll
            for (int rr = 0; rr < 4; rr++) {
                const float e = __expf(s_[j][rr] - m_run[rr]);
                rowsum[rr] += e;
                const float eo = __shfl_xor(e, 1);
                const __hip_bfloat16 b0 = __float2bfloat16(e);
                const __hip_bfloat16 b1 = __float2bfloat16(eo);
                const unsigned pk = ((unsigned)(*(const unsigned short*)&b1) << 16)
                                  | (unsigned)(*(const unsigned short*)&b0);
                if (!(lane & 1)) {
                    const int prow = wave * 16 + quad * 4 + rr;   // local 0..63
                    *(unsigned*)&pbuf[prow * 64 + ((cch ^ (prow & 7)) << 3) + (lr & 6)] = pk;
                }
            }
        }
#pragma unroll
        for (int rr = 0; rr < 4; rr++) {
#pragma unroll
            for (int off = 1; off < 16; off <<= 1)
                rowsum[rr] += __shfl_xor(rowsum[rr], off);
            l_run[rr] = l_run[rr] * scal[rr] + rowsum[rr];
        }
#pragma unroll
        for (int jd = 0; jd < 16; jd++)
#pragma unroll
            for (int rr = 0; rr < 4; rr++) acc_o[jd][rr] *= scal[rr];

        // (no barrier: pbuf rows are wave-private; compiler orders same-wave LDS ops)

        // ---- PV: O[16 x 256] += P[16 x 64] @ V^T ----
        const int pr = wave * 16 + lr;
#pragma unroll
        for (int s2 = 0; s2 < 2; ++s2) {
            const bf16x8 pa = *(const bf16x8*)&pbuf[pr * 64 + (((s2 * 4 + quad) ^ (pr & 7)) << 3)];
#pragma unroll
            for (int jd = 0; jd < 16; ++jd) {
                const int rj = jd * 16 + lr;
                const bf16x8 bv = *(const bf16x8*)&vbuf[rj * 64 + (((s2 * 4 + quad) ^ (rj & 7)) << 3)];
                acc_o[jd] = __builtin_amdgcn_mfma_f32_16x16x32_bf16(pa, bv, acc_o[jd], 0, 0, 0);
            }
        }
        __syncthreads();                 // all kbuf/vbuf reads done before next staging
    }

    // ---- branch-B staging overlaps epilogue-A global stores ----
    stageKB();
    stageVB();

    // ---- epilogue A: O / l -> bf16, cols 0..255 ----
#pragma unroll
    for (int rr = 0; rr < 4; rr++) {
        const int trow = m0 + wave * 16 + quad * 4 + rr;
        const float rinv = 1.f / l_run[rr];
        __hip_bfloat16* op = (__hip_bfloat16*)out + ((size_t)b * CL + trow) * CD;
#pragma unroll
        for (int jd = 0; jd < 16; jd++)
            op[jd * 16 + lr] = __float2bfloat16(acc_o[jd][rr] * rinv);
    }

    // ---- branch B: q_b fragments (cols 256..511), reuse qf/acc_o registers ----
    {
        const short* p0 = q + ((size_t)b * CL + qr) * 512 + CDH;
#pragma unroll
        for (int s = 0; s < 8; ++s) qf[s] = *(const bf16x8*)(p0 + s * 32 + quad * 8);
    }
    __syncthreads();                     // B K/V resident (also drains epilogue-A stores)

    {
        // QK^T: S[16 x 64], all 64 keys valid (no mask)
        f32x4 s_[4];
#pragma unroll
        for (int j = 0; j < 4; j++) s_[j] = (f32x4){0.f, 0.f, 0.f, 0.f};
#pragma unroll
        for (int s = 0; s < 8; ++s) {
#pragma unroll
            for (int j = 0; j < 4; ++j) {
                const int rj = j * 16 + lr;
                const bf16x8 bv = *(const bf16x8*)&kbuf[rj * 256 + (((s * 4 + quad) ^ (rj & 7)) << 3)];
                s_[j] = __builtin_amdgcn_mfma_f32_16x16x32_bf16(qf[s], bv, s_[j], 0, 0, 0);
            }
        }
        float tmax[4] = {-1e30f, -1e30f, -1e30f, -1e30f};
#pragma unroll
        for (int j = 0; j < 4; j++)
#pragma unroll
            for (int rr = 0; rr < 4; rr++) {
                const float v = s_[j][rr] * 0.0625f;
                s_[j][rr] = v;
                tmax[rr] = fmaxf(tmax[rr], v);
            }
#pragma unroll
        for (int rr = 0; rr < 4; rr++) {
#pragma unroll
            for (int off = 1; off < 16; off <<= 1)
                tmax[rr] = fmaxf(tmax[rr], __shfl_xor(tmax[rr], off));
        }
        float rowsum[4] = {0.f, 0.f, 0.f, 0.f};
#pragma unroll
        for (int j = 0; j < 4; j++) {
            const int cch = j * 2 + (lr >> 3);
#pragma unroll
            for (int rr = 0; rr < 4; rr++) {
                const float e = __expf(s_[j][rr] - tmax[rr]);
                rowsum[rr] += e;
                const float eo = __shfl_xor(e, 1);
                const __hip_bfloat16 b0 = __float2bfloat16(e);
                const __hip_bfloat16 b1 = __float2bfloat16(eo);
                const unsigned pk = ((unsigned)(*(const unsigned short*)&b1) << 16)
                                  | (unsigned)(*(const unsigned short*)&b0);
                if (!(lane & 1)) {
                    const int prow = wave * 16 + quad * 4 + rr;
                    *(unsigned*)&pbuf[prow * 64 + ((cch ^ (prow & 7)) << 3) + (lr & 6)] = pk;
                }
            }
        }
#pragma unroll
        for (int rr = 0; rr < 4; rr++) {
#pragma unroll
            for (int off = 1; off < 16; off <<= 1)
                rowsum[rr] += __shfl_xor(rowsum[rr], off);
        }
#pragma unroll
        for (int jd = 0; jd < 16; jd++) acc_o[jd] = (f32x4){0.f, 0.f, 0.f, 0.f};

        // PV: O_b[16 x 256]
        const int pr = wave * 16 + lr;
#pragma unroll
        for (int s2 = 0; s2 < 2; ++s2) {
            const bf16x8 pa = *(const bf16x8*)&pbuf[pr * 64 + (((s2 * 4 + quad) ^ (pr & 7)) << 3)];
#pragma unroll
            for (int jd = 0; jd < 16; ++jd) {
                const int rj = jd * 16 + lr;
                const bf16x8 bv = *(const bf16x8*)&vbuf[rj * 64 + (((s2 * 4 + quad) ^ (rj & 7)) << 3)];
                acc_o[jd] = __builtin_amdgcn_mfma_f32_16x16x32_bf16(pa, bv, acc_o[jd], 0, 0, 0);
            }
        }

        // epilogue B: cols 256..511
#pragma unroll
        for (int rr = 0; rr < 4; rr++) {
            const int trow = m0 + wave * 16 + quad * 4 + rr;
            const float rinv = 1.f / rowsum[rr];
            __hip_bfloat16* op = (__hip_bfloat16*)out + ((size_t)b * CL + trow) * CD + CDH;
#pragma unroll
            for (int jd = 0; jd < 16; jd++)
                op[jd * 16 + lr] = __float2bfloat16(acc_o[jd][rr] * rinv);
        }
    }
}

// ---------------- embedding ----------------
__global__ void embed_kernel(const int* __restrict__ cache, const int* __restrict__ seq,
                             const float* __restrict__ item, const float* __restrict__ cpos,
                             const float* __restrict__ spos, const float* __restrict__ seg,
                             float* __restrict__ h)
{
    const int row = blockIdx.x;
    const int b = row / CL, t = row - b * CL;
    const int d = threadIdx.x * 4;
    int id; const float* pos; const float* sg;
    if (t < CK) { id = cache[b * CK + t]; pos = cpos + (size_t)t * CD; sg = seg; }
    else { const int tt = t - CK; id = seq[b * CW + tt]; pos = spos + (size_t)tt * CD; sg = seg + CD; }
    const float4 ev = *(const float4*)(item + (size_t)id * CD + d);
    const float4 pv = *(const float4*)(pos + d);
    const float4 sv = *(const float4*)(sg + d);
    float4 r; r.x = ev.x + pv.x + sv.x; r.y = ev.y + pv.y + sv.y;
    r.z = ev.z + pv.z + sv.z; r.w = ev.w + pv.w + sv.w;
    *(float4*)(h + (size_t)row * CD + d) = r;
}

// ---------------- layernorm -> bf16, wave-per-row (no LDS, no barriers) ----------------
__global__ __launch_bounds__(256) void ln_kernel(const float* __restrict__ h, const float* __restrict__ g,
                                                 const float* __restrict__ bb, __hip_bfloat16* __restrict__ out)
{
    const int row = blockIdx.x * 4 + (threadIdx.x >> 6);
    const int lane = threadIdx.x & 63;
    const float* x = h + (size_t)row * CD + lane * 8;
    const float4 a = *(const float4*)(x);
    const float4 c = *(const float4*)(x + 4);
    float s  = a.x + a.y + a.z + a.w + c.x + c.y + c.z + c.w;
    float s2 = a.x*a.x + a.y*a.y + a.z*a.z + a.w*a.w
             + c.x*c.x + c.y*c.y + c.z*c.z + c.w*c.w;
#pragma unroll
    for (int off = 32; off; off >>= 1) {
        s  += __shfl_xor(s, off);
        s2 += __shfl_xor(s2, off);
    }
    const float mu = s * (1.f / CD);
    const float var = s2 * (1.f / CD) - mu * mu;
    const float rs = rsqrtf(var + 1e-5f);
    const float4 g0 = *(const float4*)(g + lane * 8);
    const float4 g1 = *(const float4*)(g + lane * 8 + 4);
    const float4 b0 = *(const float4*)(bb + lane * 8);
    const float4 b1 = *(const float4*)(bb + lane * 8 + 4);
    float v[8] = { (a.x-mu)*rs*g0.x + b0.x, (a.y-mu)*rs*g0.y + b0.y,
                   (a.z-mu)*rs*g0.z + b0.z, (a.w-mu)*rs*g0.w + b0.w,
                   (c.x-mu)*rs*g1.x + b1.x, (c.y-mu)*rs*g1.y + b1.y,
                   (c.z-mu)*rs*g1.z + b1.z, (c.w-mu)*rs*g1.w + b1.w };
    bf16x8 ov;
#pragma unroll
    for (int kk = 0; kk < 8; kk++) {
        const __hip_bfloat16 hb = __float2bfloat16(v[kk]);
        ov[kk] = *(const short*)&hb;
    }
    *(bf16x8*)(out + (size_t)row * CD + lane * 8) = ov;
}

// ---------------- final LN + logits ----------------
__global__ __launch_bounds__(256) void final_kernel(const float* __restrict__ h, const float* __restrict__ g,
                                                    const float* __restrict__ bb, const float* __restrict__ wev,
                                                    const float* __restrict__ bev, float* __restrict__ out)
{
    const int idx = blockIdx.x;
    const int b = idx >> 6, t = idx & 63;
    const float* x = h + ((size_t)b * CL + t) * CD;
    const int tid = threadIdx.x, wv = tid >> 6, lane = tid & 63;
    const float2 v = *(const float2*)(x + tid * 2);
    float s = v.x + v.y, s2 = v.x * v.x + v.y * v.y;
    __shared__ float red[8];
#pragma unroll
    for (int off = 32; off; off >>= 1) { s += __shfl_down(s, off); s2 += __shfl_down(s2, off); }
    if (lane == 0) { red[wv] = s; red[4 + wv] = s2; }
    __syncthreads();
    s = red[0] + red[1] + red[2] + red[3];
    s2 = red[4] + red[5] + red[6] + red[7];
    const float mu = s * (1.f / CD);
    const float var = s2 * (1.f / CD) - mu * mu;
    const float rs = rsqrtf(var + 1e-5f);
    const float2 gg = *(const float2*)(g + tid * 2);
    const float2 bv = *(const float2*)(bb + tid * 2);
    const float2 wv2 = *(const float2*)(wev + tid * 2);
    float val = ((v.x - mu) * rs * gg.x + bv.x) * wv2.x + ((v.y - mu) * rs * gg.y + bv.y) * wv2.y;
#pragma unroll
    for (int off = 32; off; off >>= 1) val += __shfl_down(val, off);
    __syncthreads();
    if (lane == 0) red[wv] = val;
    __syncthreads();
    if (tid == 0) out[idx] = red[0] + red[1] + red[2] + red[3] + bev[0];
}

// ---------------- transpose-convert: fp32 [z][R][C] -> bf16 [z][C][R] ----------------
__global__ void transpose_f32(const float* __restrict__ in, __hip_bfloat16* __restrict__ out,
                              int R, int Cc, long inzs, long outzs)
{
    __shared__ float tile[32][33];
    const size_t zi = (size_t)blockIdx.z * inzs;
    const size_t zo = (size_t)blockIdx.z * outzs;
    const int c0 = blockIdx.x * 32, r0 = blockIdx.y * 32;
    const int tx = threadIdx.x, ty = threadIdx.y;
#pragma unroll
    for (int i = ty; i < 32; i += 8)
        tile[i][tx] = in[zi + (size_t)(r0 + i) * Cc + c0 + tx];
    __syncthreads();
#pragma unroll
    for (int i = ty; i < 32; i += 8)
        out[zo + (size_t)(c0 + i) * R + r0 + tx] = __float2bfloat16(tile[tx][i]);
}

extern "C" void kernel_launch(void* const* d_in, const int* in_sizes, int n_in,
                              void* d_out, int out_size, void* d_ws, size_t ws_size,
                              hipStream_t stream)
{
    const int*   cache = (const int*)d_in[0];
    const int*   seq   = (const int*)d_in[1];
    const float* item  = (const float*)d_in[2];
    const float* cpos  = (const float*)d_in[3];
    const float* spos  = (const float*)d_in[4];
    const float* seg   = (const float*)d_in[5];
    const float* wq_s  = (const float*)d_in[6];
    const float* wk_s  = (const float*)d_in[7];
    const float* wv_s  = (const float*)d_in[8];
    const float* wq_c  = (const float*)d_in[9];
    const float* wk_c  = (const float*)d_in[10];
    const float* wv_c  = (const float*)d_in[11];
    const float* w_out = (const float*)d_in[12];
    const float* b_out = (const float*)d_in[13];
    const float* ln1_g = (const float*)d_in[14];
    const float* ln1_b = (const float*)d_in[15];
    const float* ln2_g = (const float*)d_in[16];
    const float* ln2_b = (const float*)d_in[17];
    const float* w_ff1 = (const float*)d_in[18];
    const float* b_ff1 = (const float*)d_in[19];
    const float* w_ff2 = (const float*)d_in[20];
    const float* b_ff2 = (const float*)d_in[21];
    const float* fin_g = (const float*)d_in[22];
    const float* fin_b = (const float*)d_in[23];
    const float* w_ev  = (const float*)d_in[24];
    const float* b_ev  = (const float*)d_in[25];

    // ---- workspace layout (~237 MiB) ----
    char* p = (char*)d_ws;
    auto alloc = [&](size_t bytes) { char* r = p; p += (bytes + 255) & ~(size_t)255; return (void*)r; };
    float* h    = (float*)alloc((size_t)CROWS * CD * 4);           // 69.2 MB
    short* hnat = (short*)alloc((size_t)CROWS * CD * 2);           // 34.6 MB  (hn, later attn)
    short* q    = (short*)alloc((size_t)CROWS * 512 * 2);          // 34.6 MB  (q_a | q_b)
    short* ka   = (short*)alloc((size_t)CB * CW * CDH * 2);        // 16.8 MB
    short* vt   = (short*)alloc((size_t)CB * CDH * CW * 2);        // 16.8 MB
    short* kb   = (short*)alloc((size_t)CB * 64 * CDH * 2);        // 0.5 MB
    short* vbT  = (short*)alloc((size_t)CB * CDH * 64 * 2);        // 0.5 MB
    short* sb   = (short*)alloc((size_t)CB * CL * 64 * 2);         // 4.3 MB (unused)
    short* big  = (short*)alloc((size_t)4 * CL * CW * 2);          // 34.6 MB (spare)
    short* wqT  = (short*)alloc((size_t)CNL * 512 * CD * 2);       // 2.1 MB
    short* wksT = (short*)alloc((size_t)CNL * CDH * CD * 2);
    short* wvsT = (short*)alloc((size_t)CNL * CDH * CD * 2);
    short* wkcT = (short*)alloc((size_t)CNL * CDH * CD * 2);
    short* wvcT = (short*)alloc((size_t)CNL * CDH * CD * 2);
    short* woT  = (short*)alloc((size_t)CNL * CD * CD * 2);
    short* wf1T = (short*)alloc((size_t)CNL * CDFF * CD * 2);
    short* wf2T = (short*)alloc((size_t)CNL * CD * CDFF * 2);
    // FFN intermediate (16896 x 2048 bf16 = 69.2 MB) aliases q..sb (~73.5 MB),
    // all dead during the FFN phase (recomputed every layer from hnat).
    short* ffbig = q;
    (void)big; (void)sb;

    const dim3 tb(32, 8);
    const long zqk = (long)CD * CDH;      // 131072
    const long zqT = (long)512 * CD;      // 262144
    transpose_f32<<<dim3(CDH/32, CD/32, CNL), tb, 0, stream>>>(wq_s, (__hip_bfloat16*)wqT, CD, CDH, zqk, zqT);
    transpose_f32<<<dim3(CDH/32, CD/32, CNL), tb, 0, stream>>>(wq_c, (__hip_bfloat16*)(wqT + (size_t)CDH * CD), CD, CDH, zqk, zqT);
    transpose_f32<<<dim3(CDH/32, CD/32, CNL), tb, 0, stream>>>(wk_s, (__hip_bfloat16*)wksT, CD, CDH, zqk, zqk);
    transpose_f32<<<dim3(CDH/32, CD/32, CNL), tb, 0, stream>>>(wv_s, (__hip_bfloat16*)wvsT, CD, CDH, zqk, zqk);
    transpose_f32<<<dim3(CDH/32, CD/32, CNL), tb, 0, stream>>>(wk_c, (__hip_bfloat16*)wkcT, CD, CDH, zqk, zqk);
    transpose_f32<<<dim3(CDH/32, CD/32, CNL), tb, 0, stream>>>(wv_c, (__hip_bfloat16*)wvcT, CD, CDH, zqk, zqk);
    transpose_f32<<<dim3(CD/32, CD/32, CNL), tb, 0, stream>>>(w_out, (__hip_bfloat16*)woT, CD, CD, (long)CD*CD, (long)CD*CD);
    transpose_f32<<<dim3(CDFF/32, CD/32, CNL), tb, 0, stream>>>(w_ff1, (__hip_bfloat16*)wf1T, CD, CDFF, (long)CD*CDFF, (long)CD*CDFF);
    transpose_f32<<<dim3(CD/32, CDFF/32, CNL), tb, 0, stream>>>(w_ff2, (__hip_bfloat16*)wf2T, CDFF, CD, (long)CD*CDFF, (long)CD*CDFF);

    embed_kernel<<<CROWS, 128, 0, stream>>>(cache, seq, item, cpos, spos, seg, h);

    const int mtilesR = CROWS / 128;          // 264

    for (int l = 0; l < CNL; ++l) {
        const short* wqTl  = wqT  + (size_t)l * 512 * CD;
        const short* wksTl = wksT + (size_t)l * CDH * CD;
        const short* wvsTl = wvsT + (size_t)l * CDH * CD;
        const short* wkcTl = wkcT + (size_t)l * CDH * CD;
        const short* wvcTl = wvcT + (size_t)l * CDH * CD;
        const short* woTl  = woT  + (size_t)l * CD * CD;
        const short* wf1Tl = wf1T + (size_t)l * CDFF * CD;
        const short* wf2Tl = wf2T + (size_t)l * CD * CDFF;

        ln_kernel<<<CROWS / 4, 256, 0, stream>>>(h, ln1_g + l * CD, ln1_b + l * CD, (__hip_bfloat16*)hnat);

        // q = hn @ [wq_s | wq_c]   (CROWS x 512)
        gemm_bt<<<dim3(512/128, mtilesR, 1), 256, 0, stream>>>(hnat, wqTl, q, nullptr,
            CROWS, 512, CD, CD, CD, 512, 0, 0, 0, 1.f, 0, 1);
        // k_a from hn_seq (batched over 16)
        gemm_bt<<<dim3(CDH/128, CW/128, CB), 256, 0, stream>>>(hnat + (size_t)CK * CD, wksTl, ka, nullptr,
            CW, CDH, CD, CD, CD, CDH, (long)CL * CD, 0, (long)CW * CDH, 1.f, 0, 1);
        // k_b  (M=64, N=256)
        gemm_bt<<<dim3(CDH/128, 1, CB), 256, 0, stream>>>(hnat, wkcTl, kb, nullptr,
            64, CDH, CD, CD, CD, CDH, (long)CL * CD, 0, (long)64 * CDH, 1.f, 0, 1);
        // vbT[d][key] = v_b^T  (M=256, N=64)
        gemm_bt<<<dim3(1, CDH/128, CB), 256, 0, stream>>>(wvcTl, hnat, vbT, nullptr,
            CDH, 64, CD, CD, CD, 64, 0, (long)CL * CD, (long)CDH * 64, 1.f, 0, 1);
        // vt[d][w] = v_a^T  (M=256, N=2048)
        gemm_bt<<<dim3(CW/128, CDH/128, CB), 256, 0, stream>>>(wvsTl, hnat + (size_t)CK * CD, vt, nullptr,
            CDH, CW, CD, CD, CD, CW, 0, (long)CL * CD, (long)CDH * CW, 1.f, 0, 1);

        // ---- branches A + B fused: flash attention -> hnat cols [0,512) ----
        flash_a<<<dim3(528), 256, 0, stream>>>(q, ka, vt, kb, vbT, hnat);

        // h += attn @ w_out + b_out
        gemm_bt<<<dim3(CD/128, mtilesR, 1), 256, 0, stream>>>(hnat, woTl, h, b_out + l * CD,
            CROWS, CD, CD, CD, CD, CD, 0, 0, 0, 1.f, 3, 1);

        ln_kernel<<<CROWS / 4, 256, 0, stream>>>(h, ln2_g + l * CD, ln2_b + l * CD, (__hip_bfloat16*)hnat);

        // FFN in 2 row chunks; intermediate aliases dead q..sb region.
        for (int c = 0; c < NCH; ++c) {
            const size_t r0 = (size_t)c * RCH2;
            gemm_bt<<<dim3(CDFF/128, RCH2/128, 1), 256, 0, stream>>>(hnat + r0 * CD, wf1Tl, ffbig, b_ff1 + l * CDFF,
                RCH2, CDFF, CD, CD, CD, CDFF, 0, 0, 0, 1.f, 1, 1);
            gemm_bt<<<dim3(CD/128, RCH2/128, 1), 256, 0, stream>>>(ffbig, wf2Tl, h + r0 * CD, b_ff2 + l * CD,
                RCH2, CD, CDFF, CDFF, CDFF, CD, 0, 0, 0, 1.f, 3, 1);
        }
    }

    final_kernel<<<CB * CK, 256, 0, stream>>>(h, fin_g, fin_b, w_ev, b_ev, (float*)d_out);
}